// Round 3
// baseline (19251.030 us; speedup 1.0000x reference)
//
#include <hip/hip_runtime.h>
#include <math.h>

namespace {

constexpr int NB  = 256;    // batch
constexpr int NT  = 20;     // time steps
constexpr int NR  = 100;    // regions
constexpr int IND = 300;    // in_dim
constexpr int NH  = 1024;   // num_hid
constexpr int VD  = 2048;   // v_dim
constexpr int H4  = 4096;   // 4*num_hid
constexpr int VOC = 10000;  // vocab

// packed K' layout: per original k, 3 slots. A side: [hi, lo, hi]; B side: [hi, hi, lo]
// => products per k: Ah*Bh + Al*Bh + Ah*Bl  (drop Al*Bl, rel err ~2^-16)
constexpr int KGV = 7072;   // gates_v K' : 3*(1024+1024+300)=7044 -> pad 7072
constexpr int KGC = 12288;  // gates_c K' : 3*(2048+1024+1024)
constexpr int KHA = 3072;   // ha K'      : 3*1024
constexpr int KCL = 3072;   // cls K'     : 3*1024

typedef short  s8v  __attribute__((ext_vector_type(8)));
typedef float  f4v  __attribute__((ext_vector_type(4)));

__device__ __forceinline__ float sigm(float x) { return 1.f / (1.f + expf(-x)); }

__device__ __forceinline__ unsigned short f2b(float x) {
  return __builtin_bit_cast(unsigned short, (__bf16)x);
}
__device__ __forceinline__ float b2f(unsigned short u) {
  return (float)__builtin_bit_cast(__bf16, u);
}
// A-side split pack: slots (hi, lo, hi)
__device__ __forceinline__ void pack3(unsigned short* p, float x) {
  unsigned short h = f2b(x);
  unsigned short l = f2b(x - b2f(h));
  p[0] = h; p[1] = l; p[2] = h;
}

// =================== bf16 MFMA GEMM ===================
// A: [M, lda] bf16(ushort)  (or fp32 when A_F32: converted hi-only on stage)
// Bt: [N, ldb] bf16 rows (pre-transposed)
// C = A@B (+bias) (+Cin), fp32 out (or bf16 when OUT_BF16)
// M multiple of BM; N guarded; Kp multiple of 32 (pad columns must be zero).
template<int BM, int BN, bool A_F32, bool OUT_BF16>
__global__ __launch_bounds__(256)
void gemm_mfma(const void* __restrict__ Av, int lda,
               const unsigned short* __restrict__ Bt, int ldb,
               void* __restrict__ Cv, int ldc,
               const float* __restrict__ bias,
               const float* __restrict__ Cin, int ldcin,
               int M, int N, int Kp)
{
  constexpr int WM = BM / 2, WN = BN / 2;   // wave tile (4 waves, 2x2)
  constexpr int FM = WM / 16, FN = WN / 16;
  __shared__ unsigned short As[BM][40];      // +8 pad: 80B rows -> 2-way bank alias (free)
  __shared__ unsigned short Bs[BN][40];
  const int tid  = threadIdx.x;
  const int wid  = tid >> 6, lane = tid & 63;
  const int wm   = (wid >> 1) * WM, wn = (wid & 1) * WN;
  const int m0   = blockIdx.y * BM, n0 = blockIdx.x * BN;

  f4v acc[FM][FN] = {};

  for (int k0 = 0; k0 < Kp; k0 += 32) {
    // ---- stage A tile BM x 32 ----
    if constexpr (A_F32) {
      const float* A = (const float*)Av;
#pragma unroll
      for (int it = 0; it < BM / 32; ++it) {
        const int r = it * 32 + (tid >> 3);
        const int c = (tid & 7) * 4;
        const float4 v = *(const float4*)(A + (size_t)(m0 + r) * lda + k0 + c);
        ushort4 w;
        w.x = f2b(v.x); w.y = f2b(v.y); w.z = f2b(v.z); w.w = f2b(v.w);
        *(ushort4*)&As[r][c] = w;
      }
    } else {
      const unsigned short* A = (const unsigned short*)Av;
#pragma unroll
      for (int it = 0; it < BM / 64; ++it) {
        const int r = it * 64 + (tid >> 2);
        const int c = (tid & 3) * 8;
        *(s8v*)&As[r][c] = *(const s8v*)(A + (size_t)(m0 + r) * lda + k0 + c);
      }
    }
    // ---- stage B tile BN x 32 (rows are n), N-guarded ----
#pragma unroll
    for (int it = 0; it < BN / 64; ++it) {
      const int r = it * 64 + (tid >> 2);
      const int c = (tid & 3) * 8;
      const int gn = n0 + r;
      s8v v = {0, 0, 0, 0, 0, 0, 0, 0};
      if (gn < N) v = *(const s8v*)(Bt + (size_t)gn * ldb + k0 + c);
      *(s8v*)&Bs[r][c] = v;
    }
    __syncthreads();

    // ---- fragments: row/col = lane&15, k-chunk = (lane>>4)*8 ----
    s8v a[FM], b[FN];
#pragma unroll
    for (int i = 0; i < FM; ++i)
      a[i] = *(const s8v*)&As[wm + i * 16 + (lane & 15)][(lane >> 4) * 8];
#pragma unroll
    for (int j = 0; j < FN; ++j)
      b[j] = *(const s8v*)&Bs[wn + j * 16 + (lane & 15)][(lane >> 4) * 8];
#pragma unroll
    for (int i = 0; i < FM; ++i)
#pragma unroll
      for (int j = 0; j < FN; ++j)
        acc[i][j] = __builtin_amdgcn_mfma_f32_16x16x32_bf16(a[i], b[j], acc[i][j], 0, 0, 0);
    __syncthreads();
  }

  // ---- epilogue: C/D layout col=lane&15, row=(lane>>4)*4+reg ----
  const int cr = (lane >> 4) * 4, cc = lane & 15;
#pragma unroll
  for (int i = 0; i < FM; ++i) {
#pragma unroll
    for (int j = 0; j < FN; ++j) {
      const int gn = n0 + wn + j * 16 + cc;
      if (gn >= N) continue;
#pragma unroll
      for (int r = 0; r < 4; ++r) {
        const int gm = m0 + wm + i * 16 + cr + r;
        float v = acc[i][j][r];
        if (bias) v += bias[gn];
        if (Cin)  v += Cin[(size_t)gm * ldcin + gn];
        if constexpr (OUT_BF16) ((unsigned short*)Cv)[(size_t)gm * ldc + gn] = f2b(v);
        else                    ((float*)Cv)[(size_t)gm * ldc + gn] = v;
      }
    }
  }
}

// =================== fp32 fallback GEMM (setup-only, verified R1) ===================
__global__ __launch_bounds__(256)
void gemm_f32(const float* __restrict__ Ap, int lda,
              const float* __restrict__ Bp, int ldb,
              float* __restrict__ Cp, int ldc,
              const float* __restrict__ bias,
              const float* __restrict__ Cin, int ldcin,
              int M, int N, int K)
{
  __shared__ float As[16][64];
  __shared__ float Bs[16][64];
  const int n0 = blockIdx.x * 64;
  const int m0 = blockIdx.y * 64;
  const int tid = threadIdx.x;
  const int tx = tid & 15, ty = tid >> 4;
  float acc[4][4] = {};

  for (int k0 = 0; k0 < K; k0 += 16) {
    {
      const int e = tid << 2;
      const int m = e >> 4;
      const int k = e & 15;
      const int gm = m0 + m, gk = k0 + k;
      float4 v = make_float4(0.f, 0.f, 0.f, 0.f);
      if (gm < M) {
        const float* src = Ap + (size_t)gm * lda + gk;
        if (gk + 3 < K) v = *(const float4*)src;
        else {
          if (gk     < K) v.x = src[0];
          if (gk + 1 < K) v.y = src[1];
          if (gk + 2 < K) v.z = src[2];
          if (gk + 3 < K) v.w = src[3];
        }
      }
      As[k][m] = v.x; As[k + 1][m] = v.y; As[k + 2][m] = v.z; As[k + 3][m] = v.w;
    }
    {
      const int e = tid << 2;
      const int k = e >> 6;
      const int n = e & 63;
      const int gk = k0 + k, gn = n0 + n;
      float4 v = make_float4(0.f, 0.f, 0.f, 0.f);
      if (gk < K) {
        const float* src = Bp + (size_t)gk * ldb + gn;
        if (gn + 3 < N) v = *(const float4*)src;
        else {
          if (gn     < N) v.x = src[0];
          if (gn + 1 < N) v.y = src[1];
          if (gn + 2 < N) v.z = src[2];
          if (gn + 3 < N) v.w = src[3];
        }
      }
      Bs[k][n] = v.x; Bs[k][n + 1] = v.y; Bs[k][n + 2] = v.z; Bs[k][n + 3] = v.w;
    }
    __syncthreads();
#pragma unroll
    for (int k = 0; k < 16; ++k) {
      const float a0 = As[k][ty * 4 + 0], a1 = As[k][ty * 4 + 1];
      const float a2 = As[k][ty * 4 + 2], a3 = As[k][ty * 4 + 3];
      const float b0 = Bs[k][tx * 4 + 0], b1 = Bs[k][tx * 4 + 1];
      const float b2 = Bs[k][tx * 4 + 2], b3 = Bs[k][tx * 4 + 3];
      acc[0][0] += a0 * b0; acc[0][1] += a0 * b1; acc[0][2] += a0 * b2; acc[0][3] += a0 * b3;
      acc[1][0] += a1 * b0; acc[1][1] += a1 * b1; acc[1][2] += a1 * b2; acc[1][3] += a1 * b3;
      acc[2][0] += a2 * b0; acc[2][1] += a2 * b1; acc[2][2] += a2 * b2; acc[2][3] += a2 * b3;
      acc[3][0] += a3 * b0; acc[3][1] += a3 * b1; acc[3][2] += a3 * b2; acc[3][3] += a3 * b3;
    }
    __syncthreads();
  }
#pragma unroll
  for (int i = 0; i < 4; ++i) {
    const int gm = m0 + ty * 4 + i;
    if (gm >= M) continue;
#pragma unroll
    for (int j = 0; j < 4; ++j) {
      const int gn = n0 + tx * 4 + j;
      if (gn >= N) continue;
      float v = acc[i][j];
      if (bias) v += bias[gn];
      if (Cin)  v += Cin[(size_t)gm * ldcin + gn];
      Cp[(size_t)gm * ldc + gn] = v;
    }
  }
}

// =================== weight transpose+convert ===================
// src [K,N] f32 -> dst [N, dstld] bf16 at column offset coff.
// mode 0: packed B slots (hi,hi,lo) at 3k; mode 1: plain hi at k.
__global__ void convB_k(const float* __restrict__ src, int srcld, int K, int N,
                        unsigned short* __restrict__ dst, int dstld, int coff, int mode)
{
  __shared__ float t[32][33];
  const int kb = blockIdx.x * 32, nb = blockIdx.y * 32;
  const int tx = threadIdx.x & 31, ty = threadIdx.x >> 5;  // 256 thr: 32x8
#pragma unroll
  for (int i = 0; i < 32; i += 8) {
    const int k = kb + ty + i, n = nb + tx;
    t[ty + i][tx] = (k < K && n < N) ? src[(size_t)k * srcld + n] : 0.f;
  }
  __syncthreads();
#pragma unroll
  for (int i = 0; i < 32; i += 8) {
    const int n = nb + ty + i, k = kb + tx;
    if (n >= N || k >= K) continue;
    const float x = t[tx][ty + i];
    if (mode == 0) {
      const unsigned short h = f2b(x);
      const unsigned short l = f2b(x - b2f(h));
      unsigned short* p = dst + (size_t)n * dstld + coff + 3 * k;
      p[0] = h; p[1] = h; p[2] = l;
    } else {
      dst[(size_t)n * dstld + coff + k] = f2b(x);
    }
  }
}

// zero columns [c0, ld) for rows [0, N)
__global__ void zpad_k(unsigned short* __restrict__ dst, int ld, int c0, int N)
{
  const int w = ld - c0;
  const int idx = blockIdx.x * 256 + threadIdx.x;
  if (idx >= N * w) return;
  dst[(size_t)(idx / w) * ld + c0 + (idx % w)] = 0;
}

// =================== small fused kernels ===================
__global__ void feat_mean_k(const float* __restrict__ feat, float* __restrict__ fm)
{
  const int idx = blockIdx.x * 256 + threadIdx.x;   // NB*VD
  if (idx >= NB * VD) return;
  const int d = idx % VD, b = idx / VD;
  const float* base = feat + (size_t)b * NR * VD + d;
  float s = 0.f;
  for (int r = 0; r < NR; ++r) s += base[(size_t)r * VD];
  fm[idx] = s * (1.f / NR);
}

// X2all[(b*NT+t)*900 + 3d + s] packed from VINP (t==0) or emb[caption]
__global__ void build_x2_k(const int* __restrict__ cap, const float* __restrict__ emb,
                           const float* __restrict__ vinp, unsigned short* __restrict__ X2)
{
  const int idx = blockIdx.x * 256 + threadIdx.x;   // NB*NT*IND
  if (idx >= NB * NT * IND) return;
  const int d = idx % IND;
  const int bt = idx / IND;
  const int t = bt % NT, b = bt / NT;
  float v;
  if (t == 0) v = vinp[b * IND + d];
  else        v = emb[(size_t)cap[b * (NT - 1) + (t - 1)] * IND + d];
  pack3(&X2[(size_t)bt * 900 + 3 * d], v);
}

// copy X2all[:,t,:] into A2v x-segment
__global__ void x2step_k(const unsigned short* __restrict__ X2, unsigned short* __restrict__ A2v, int t)
{
  const int idx = blockIdx.x * 256 + threadIdx.x;   // NB*900
  if (idx >= NB * 900) return;
  const int b = idx / 900, c = idx % 900;
  A2v[(size_t)b * KGV + 6144 + c] = X2[((size_t)b * NT + t) * 900 + c];
}

// LSTM-v pointwise: gates -> c_v update; h_v packed into A2c@6144 (this step's ha/gates_c)
// AND into A2v@3072 (next step's gates_v W_hh_v term)  <-- was missing in R2
__global__ void lstm_pw_v_k(const float* __restrict__ gates, float* __restrict__ cv,
                            unsigned short* __restrict__ A2c, unsigned short* __restrict__ A2v)
{
  const int idx = blockIdx.x * 256 + threadIdx.x;   // NB*NH
  if (idx >= NB * NH) return;
  const int n = idx & (NH - 1), b = idx >> 10;
  const float* g = gates + (size_t)b * H4;
  const float c2 = sigm(g[NH + n]) * cv[idx] + sigm(g[n]) * tanhf(g[2 * NH + n]);
  const float h2 = sigm(g[3 * NH + n]) * tanhf(c2);
  cv[idx] = c2;
  unsigned short h = f2b(h2);
  unsigned short l = f2b(h2 - b2f(h));
  unsigned short* p0 = &A2c[(size_t)b * KGC + 6144 + 3 * n];
  unsigned short* p1 = &A2v[(size_t)b * KGV + 3072 + 3 * n];
  p0[0] = h; p0[1] = l; p0[2] = h;
  p1[0] = h; p1[1] = l; p1[2] = h;
}

// LSTM-c pointwise: -> c_c update; h_c packed into A2v@0 (next step), A2c@9216 (next step), OUTH2 row
__global__ void lstm_pw_c_k(const float* __restrict__ gates, float* __restrict__ cc,
                            unsigned short* __restrict__ A2v, unsigned short* __restrict__ A2c,
                            unsigned short* __restrict__ outh2, int t)
{
  const int idx = blockIdx.x * 256 + threadIdx.x;   // NB*NH
  if (idx >= NB * NH) return;
  const int n = idx & (NH - 1), b = idx >> 10;
  const float* g = gates + (size_t)b * H4;
  const float c2 = sigm(g[NH + n]) * cc[idx] + sigm(g[n]) * tanhf(g[2 * NH + n]);
  const float h2 = sigm(g[3 * NH + n]) * tanhf(c2);
  cc[idx] = c2;
  unsigned short h = f2b(h2);
  unsigned short l = f2b(h2 - b2f(h));
  unsigned short* p0 = &A2v[(size_t)b * KGV + 3 * n];
  unsigned short* p1 = &A2c[(size_t)b * KGC + 9216 + 3 * n];
  unsigned short* p2 = &outh2[((size_t)b * NT + t) * KCL + 3 * n];
  p0[0] = h; p0[1] = l; p0[2] = h;
  p1[0] = h; p1[1] = l; p1[2] = h;
  p2[0] = h; p2[1] = l; p2[2] = h;
}

// attention logits: one wave per (b,r); VA16 bf16 [NB*NR, NH]
__global__ void att_logits_k(const unsigned short* __restrict__ va16, const float* __restrict__ ha,
                             const float* __restrict__ Wa, const float* __restrict__ ba,
                             float* __restrict__ logits)
{
  const int wave = (blockIdx.x * 256 + threadIdx.x) >> 6;
  const int lane = threadIdx.x & 63;
  if (wave >= NB * NR) return;
  const int b = wave / NR;
  const unsigned short* vrow = va16 + (size_t)wave * NH;
  const float* hrow = ha + (size_t)b * NH;
  float s = 0.f;
#pragma unroll
  for (int it = 0; it < 2; ++it) {
    const int base = (lane + it * 64) * 8;
    const s8v v = *(const s8v*)(vrow + base);
    const float4 h0 = *(const float4*)(hrow + base);
    const float4 h1 = *(const float4*)(hrow + base + 4);
    const float4 w0 = *(const float4*)(Wa + base);
    const float4 w1 = *(const float4*)(Wa + base + 4);
    s += tanhf(b2f((unsigned short)v[0]) + h0.x) * w0.x;
    s += tanhf(b2f((unsigned short)v[1]) + h0.y) * w0.y;
    s += tanhf(b2f((unsigned short)v[2]) + h0.z) * w0.z;
    s += tanhf(b2f((unsigned short)v[3]) + h0.w) * w0.w;
    s += tanhf(b2f((unsigned short)v[4]) + h1.x) * w1.x;
    s += tanhf(b2f((unsigned short)v[5]) + h1.y) * w1.y;
    s += tanhf(b2f((unsigned short)v[6]) + h1.z) * w1.z;
    s += tanhf(b2f((unsigned short)v[7]) + h1.w) * w1.w;
  }
  for (int o = 32; o; o >>= 1) s += __shfl_down(s, o);
  if (lane == 0) logits[wave] = s + ba[0];
}

__global__ void att_softmax_k(const float* __restrict__ logits, float* __restrict__ att, int t)
{
  const int b = blockIdx.x;
  const int tx = threadIdx.x;       // 128
  const int lane = tx & 63, wid = tx >> 6;
  __shared__ float red[2];
  float v = (tx < NR) ? logits[b * NR + tx] : -3.4e38f;
  float m = v;
  for (int o = 32; o; o >>= 1) m = fmaxf(m, __shfl_xor(m, o));
  if (lane == 0) red[wid] = m;
  __syncthreads();
  m = fmaxf(red[0], red[1]);
  const float e = (tx < NR) ? expf(v - m) : 0.f;
  float s = e;
  for (int o = 32; o; o >>= 1) s += __shfl_xor(s, o);
  __syncthreads();
  if (lane == 0) red[wid] = s;
  __syncthreads();
  s = red[0] + red[1];
  if (tx < NR) att[(size_t)b * NT * NR + (size_t)t * NR + tx] = e / s;
}

// feat_hat packed directly into A2c@0
__global__ void feat_hat_k(const float* __restrict__ feat, const float* __restrict__ att,
                           unsigned short* __restrict__ A2c, int t)
{
  const int idx = blockIdx.x * 256 + threadIdx.x;   // NB*VD
  if (idx >= NB * VD) return;
  const int d = idx % VD, b = idx / VD;
  const float* arow = att + (size_t)b * NT * NR + (size_t)t * NR;
  const float* base = feat + (size_t)b * NR * VD + d;
  float s = 0.f;
  for (int r = 0; r < NR; ++r) s += arow[r] * base[(size_t)r * VD];
  pack3(&A2c[(size_t)b * KGC + 3 * d], s * (1.f / NR));
}

inline void gemmF(hipStream_t st, const float* A, int lda, const float* B, int ldb,
                  float* C, int ldc, const float* bias, int M, int N, int K)
{
  dim3 g((N + 63) / 64, (M + 63) / 64);
  gemm_f32<<<g, 256, 0, st>>>(A, lda, B, ldb, C, ldc, bias, nullptr, 0, M, N, K);
}

inline void convB(hipStream_t st, const float* src, int srcld, int K, int N,
                  unsigned short* dst, int dstld, int coff, int mode)
{
  dim3 g((K + 31) / 32, (N + 31) / 32);
  convB_k<<<g, 256, 0, st>>>(src, srcld, K, N, dst, dstld, coff, mode);
}

} // namespace

extern "C" void kernel_launch(void* const* d_in, const int* in_sizes, int n_in,
                              void* d_out, int out_size, void* d_ws, size_t ws_size,
                              hipStream_t stream)
{
  const int*   caption = (const int*)  d_in[0];
  const float* feat    = (const float*)d_in[1];
  const float* emb     = (const float*)d_in[2];
  const float* W_vin   = (const float*)d_in[3];
  const float* b_vin   = (const float*)d_in[4];
  const float* W_ih_v  = (const float*)d_in[5];   // [3372, 4096]
  const float* W_hh_v  = (const float*)d_in[6];   // [1024, 4096]
  const float* b_v     = (const float*)d_in[7];
  const float* W_va    = (const float*)d_in[8];   // [2048, 1024]
  const float* b_va    = (const float*)d_in[9];
  const float* W_ha    = (const float*)d_in[10];  // [1024, 1024]
  const float* b_ha    = (const float*)d_in[11];
  const float* W_a     = (const float*)d_in[12];  // [1024, 1]
  const float* b_a     = (const float*)d_in[13];
  const float* W_ih_c  = (const float*)d_in[14];  // [3072, 4096]
  const float* W_hh_c  = (const float*)d_in[15];  // [1024, 4096]
  const float* b_c     = (const float*)d_in[16];
  const float* W_cls   = (const float*)d_in[17];  // [1024, 10000]
  const float* b_cls   = (const float*)d_in[18];

  float* out_repr = (float*)d_out;                       // [NB,NT,VOC]
  float* out_att  = out_repr + (size_t)NB * NT * VOC;    // [NB,NT,NR]

  // ---- workspace layout (bytes; every size multiple of 256) ----
  char* cur = (char*)d_ws;
  auto take = [&](size_t bytes) { char* p = cur; cur += bytes; return p; };

  // zero-region (one memset): A2v, A2c, CV, CC
  unsigned short* A2v  = (unsigned short*)take((size_t)NB * KGV * 2);     // 3.62MB
  unsigned short* A2c  = (unsigned short*)take((size_t)NB * KGC * 2);     // 6.29MB
  float* CV            = (float*)take((size_t)NB * NH * 4);
  float* CC            = (float*)take((size_t)NB * NH * 4);
  const size_t ZERO_BYTES = (size_t)NB * KGV * 2 + (size_t)NB * KGC * 2
                          + 2 * (size_t)NB * NH * 4;

  float* FM            = (float*)take((size_t)NB * VD * 4);
  float* VINP          = (float*)take((size_t)NB * IND * 4);
  unsigned short* X2   = (unsigned short*)take((size_t)NB * NT * 900 * 2);
  float* FMG           = (float*)take((size_t)NB * H4 * 4);
  unsigned short* VA16 = (unsigned short*)take((size_t)NB * NR * NH * 2); // 52MB
  float* GATES         = (float*)take((size_t)NB * H4 * 4);
  float* HA            = (float*)take((size_t)NB * NH * 4);
  float* LOG           = (float*)take((size_t)NB * NR * 4);
  unsigned short* OUTH2= (unsigned short*)take((size_t)NB * NT * KCL * 2);// 31MB
  unsigned short* Wgv2t= (unsigned short*)take((size_t)H4 * KGV * 2);     // 58MB
  unsigned short* Wha2t= (unsigned short*)take((size_t)NH * KHA * 2);     // 6.3MB
  unsigned short* Wgc2t= (unsigned short*)take((size_t)H4 * KGC * 2);     // 101MB
  unsigned short* Wcls2t=(unsigned short*)take((size_t)VOC * KCL * 2);    // 61MB
  unsigned short* Wva16t=(unsigned short*)take((size_t)NH * VD * 2);      // 4.2MB

  hipMemsetAsync(A2v, 0, ZERO_BYTES, stream);

  // ---- weight conversions (per call; ~70us of BW) ----
  // gates_v B: rows = [W_ih_v[2048:3072] | W_hh_v | W_ih_v[3072:3372]], N=4096
  convB(stream, W_ih_v + (size_t)2048 * H4, H4, 1024, H4, Wgv2t, KGV, 0,    0);
  convB(stream, W_hh_v,                     H4, 1024, H4, Wgv2t, KGV, 3072, 0);
  convB(stream, W_ih_v + (size_t)3072 * H4, H4, 300,  H4, Wgv2t, KGV, 6144, 0);
  zpad_k<<<((H4 * (KGV - 7044)) + 255) / 256, 256, 0, stream>>>(Wgv2t, KGV, 7044, H4);
  // ha B
  convB(stream, W_ha, NH, 1024, NH, Wha2t, KHA, 0, 0);
  // gates_c B: rows = [W_ih_c[0:2048] | W_ih_c[2048:3072] | W_hh_c], N=4096
  convB(stream, W_ih_c,                     H4, 2048, H4, Wgc2t, KGC, 0,    0);
  convB(stream, W_ih_c + (size_t)2048 * H4, H4, 1024, H4, Wgc2t, KGC, 6144, 0);
  convB(stream, W_hh_c,                     H4, 1024, H4, Wgc2t, KGC, 9216, 0);
  // classifier B
  convB(stream, W_cls, VOC, 1024, VOC, Wcls2t, KCL, 0, 0);
  // VA B (plain hi)
  convB(stream, W_va, NH, VD, NH, Wva16t, VD, 0, 1);

  // ---- setup ----
  feat_mean_k<<<(NB * VD + 255) / 256, 256, 0, stream>>>(feat, FM);
  // VINP = FM @ W_vin + b_vin  (fp32, one-time, tiny)
  gemmF(stream, FM, VD, W_vin, IND, VINP, IND, b_vin, NB, IND, VD);
  build_x2_k<<<(NB * NT * IND + 255) / 256, 256, 0, stream>>>(caption, emb, VINP, X2);
  // FMG = FM @ W_ih_v[0:2048] + b_v  (fp32, one-time)
  gemmF(stream, FM, VD, W_ih_v, H4, FMG, H4, b_v, NB, H4, VD);
  // VA16 = bf16(features @ W_va + b_va): A fp32 converted on stage
  {
    dim3 g(NH / 128, (NB * NR) / 128);
    gemm_mfma<128, 128, true, true><<<g, 256, 0, stream>>>(
        feat, VD, Wva16t, VD, VA16, NH, b_va, nullptr, 0, NB * NR, NH, VD);
  }

  // ---- sequential decode ----
  for (int t = 0; t < NT; ++t) {
    x2step_k<<<(NB * 900 + 255) / 256, 256, 0, stream>>>(X2, A2v, t);
    // gates_v = [h_c|h_v|x_t] @ Wgv + FMG(b_v included)
    {
      dim3 g(H4 / 128, NB / 64);
      gemm_mfma<64, 128, false, false><<<g, 256, 0, stream>>>(
          A2v, KGV, Wgv2t, KGV, GATES, H4, nullptr, FMG, H4, NB, H4, KGV);
    }
    lstm_pw_v_k<<<(NB * NH + 255) / 256, 256, 0, stream>>>(GATES, CV, A2c, A2v);
    // ha = h_v @ W_ha + b_ha  (A = packed h_v segment inside A2c)
    {
      dim3 g(NH / 128, NB / 64);
      gemm_mfma<64, 128, false, false><<<g, 256, 0, stream>>>(
          A2c + 6144, KGC, Wha2t, KHA, HA, NH, b_ha, nullptr, 0, NB, NH, KHA);
    }
    att_logits_k<<<(NB * NR * 64 + 255) / 256, 256, 0, stream>>>(VA16, HA, W_a, b_a, LOG);
    att_softmax_k<<<NB, 128, 0, stream>>>(LOG, out_att, t);
    feat_hat_k<<<(NB * VD + 255) / 256, 256, 0, stream>>>(feat, out_att, A2c, t);
    // gates_c = [feat_hat|h_v|h_c] @ Wgc + b_c
    {
      dim3 g(H4 / 128, NB / 64);
      gemm_mfma<64, 128, false, false><<<g, 256, 0, stream>>>(
          A2c, KGC, Wgc2t, KGC, GATES, H4, b_c, nullptr, 0, NB, H4, KGC);
    }
    lstm_pw_c_k<<<(NB * NH + 255) / 256, 256, 0, stream>>>(GATES, CC, A2v, A2c, OUTH2, t);
  }

  // ---- classifier: out = OUTH2 @ W_cls + b_cls ----
  {
    dim3 g((VOC + 127) / 128, (NB * NT) / 128);
    gemm_mfma<128, 128, false, false><<<g, 256, 0, stream>>>(
        OUTH2, KCL, Wcls2t, KCL, out_repr, VOC, b_cls, nullptr, 0, NB * NT, VOC, KCL);
  }
}

// Round 4
// 7444.437 us; speedup vs baseline: 2.5860x; 2.5860x over previous
//
#include <hip/hip_runtime.h>
#include <math.h>

namespace {

constexpr int NB  = 256;    // batch
constexpr int NT  = 20;     // time steps
constexpr int NR  = 100;    // regions
constexpr int IND = 300;    // in_dim
constexpr int NH  = 1024;   // num_hid
constexpr int VD  = 2048;   // v_dim
constexpr int H4  = 4096;   // 4*num_hid
constexpr int VOC = 10000;  // vocab

// packed K' layout: per original k, 3 slots. A side: [hi, lo, hi]; B side: [hi, hi, lo]
// => products per k: Ah*Bh + Al*Bh + Ah*Bl  (drop Al*Bl, rel err ~2^-16)
constexpr int KGV = 7072;   // gates_v K' : 3*(1024+1024+300)=7044 -> pad 7072
constexpr int KGC = 12288;  // gates_c K' : 3*(2048+1024+1024)
constexpr int KHA = 3072;   // ha K'      : 3*1024
constexpr int KCL = 3072;   // cls K'     : 3*1024

// split-K configs
constexpr int ZGV = 4; constexpr int KSV = 1792;   // 4*1792 >= 7072, last=1696
constexpr int ZGC = 4; constexpr int KSC = 3072;
constexpr int ZHA = 2; constexpr int KSH = 1536;

typedef short  s8v  __attribute__((ext_vector_type(8)));
typedef float  f4v  __attribute__((ext_vector_type(4)));

__device__ __forceinline__ float sigm(float x) { return 1.f / (1.f + expf(-x)); }

__device__ __forceinline__ unsigned short f2b(float x) {
  return __builtin_bit_cast(unsigned short, (__bf16)x);
}
__device__ __forceinline__ float b2f(unsigned short u) {
  return (float)__builtin_bit_cast(__bf16, u);
}
// A-side split pack: slots (hi, lo, hi)
__device__ __forceinline__ void pack3(unsigned short* p, float x) {
  unsigned short h = f2b(x);
  unsigned short l = f2b(x - b2f(h));
  p[0] = h; p[1] = l; p[2] = h;
}

// =================== split-K bf16 MFMA GEMM (skinny M) ===================
// A [M,lda] bf16; Bt [N,ldb] bf16 (pre-transposed). Partial z writes
// P + z*M*N (fp32, no bias). M,N multiples of 64. K range [z*Ksplit, ...).
__global__ __launch_bounds__(256)
void gemm_sk(const unsigned short* __restrict__ A, int lda,
             const unsigned short* __restrict__ Bt, int ldb,
             float* __restrict__ P, int M, int N, int Kp, int Ksplit)
{
  __shared__ unsigned short As[64][40];   // +8 pad: 2-way bank alias (free)
  __shared__ unsigned short Bs[64][40];
  const int tid = threadIdx.x;
  const int wid = tid >> 6, lane = tid & 63;
  const int wm = (wid >> 1) * 32, wn = (wid & 1) * 32;
  const int m0 = blockIdx.y * 64, n0 = blockIdx.x * 64;
  const int kbeg = blockIdx.z * Ksplit;
  const int kend = min(Kp, kbeg + Ksplit);
  const int sr = tid >> 2, sc = (tid & 3) * 8;

  f4v acc[2][2] = {};

  for (int k0 = kbeg; k0 < kend; k0 += 32) {
    *(s8v*)&As[sr][sc] = *(const s8v*)(A  + (size_t)(m0 + sr) * lda + k0 + sc);
    *(s8v*)&Bs[sr][sc] = *(const s8v*)(Bt + (size_t)(n0 + sr) * ldb + k0 + sc);
    __syncthreads();
    const int kc = (lane >> 4) * 8, rr = lane & 15;
    s8v a0 = *(const s8v*)&As[wm + rr][kc];
    s8v a1 = *(const s8v*)&As[wm + 16 + rr][kc];
    s8v b0 = *(const s8v*)&Bs[wn + rr][kc];
    s8v b1 = *(const s8v*)&Bs[wn + 16 + rr][kc];
    acc[0][0] = __builtin_amdgcn_mfma_f32_16x16x32_bf16(a0, b0, acc[0][0], 0, 0, 0);
    acc[0][1] = __builtin_amdgcn_mfma_f32_16x16x32_bf16(a0, b1, acc[0][1], 0, 0, 0);
    acc[1][0] = __builtin_amdgcn_mfma_f32_16x16x32_bf16(a1, b0, acc[1][0], 0, 0, 0);
    acc[1][1] = __builtin_amdgcn_mfma_f32_16x16x32_bf16(a1, b1, acc[1][1], 0, 0, 0);
    __syncthreads();
  }

  float* out = P + (size_t)blockIdx.z * M * N;
  const int cr = (lane >> 4) * 4, cc = lane & 15;
#pragma unroll
  for (int i = 0; i < 2; ++i)
#pragma unroll
    for (int j = 0; j < 2; ++j)
#pragma unroll
      for (int r = 0; r < 4; ++r)
        out[(size_t)(m0 + wm + i * 16 + cr + r) * N + n0 + wn + j * 16 + cc] = acc[i][j][r];
}

// =================== bf16 MFMA GEMM (large, no split) ===================
// MINNER: blockIdx.x indexes M (consecutive blocks share B n-slice -> L2 reuse)
template<int BM, int BN, bool A_F32, bool OUT_BF16, bool MINNER>
__global__ __launch_bounds__(256)
void gemm_mfma(const void* __restrict__ Av, int lda,
               const unsigned short* __restrict__ Bt, int ldb,
               void* __restrict__ Cv, int ldc,
               const float* __restrict__ bias,
               int M, int N, int Kp)
{
  constexpr int WM = BM / 2, WN = BN / 2;
  constexpr int FM = WM / 16, FN = WN / 16;
  __shared__ unsigned short As[BM][40];
  __shared__ unsigned short Bs[BN][40];
  const int tid  = threadIdx.x;
  const int wid  = tid >> 6, lane = tid & 63;
  const int wm   = (wid >> 1) * WM, wn = (wid & 1) * WN;
  const int m0   = MINNER ? blockIdx.x * BM : blockIdx.y * BM;
  const int n0   = MINNER ? blockIdx.y * BN : blockIdx.x * BN;

  f4v acc[FM][FN] = {};

  for (int k0 = 0; k0 < Kp; k0 += 32) {
    if constexpr (A_F32) {
      const float* A = (const float*)Av;
#pragma unroll
      for (int it = 0; it < BM / 32; ++it) {
        const int r = it * 32 + (tid >> 3);
        const int c = (tid & 7) * 4;
        const float4 v = *(const float4*)(A + (size_t)(m0 + r) * lda + k0 + c);
        ushort4 w;
        w.x = f2b(v.x); w.y = f2b(v.y); w.z = f2b(v.z); w.w = f2b(v.w);
        *(ushort4*)&As[r][c] = w;
      }
    } else {
      const unsigned short* A = (const unsigned short*)Av;
#pragma unroll
      for (int it = 0; it < BM / 64; ++it) {
        const int r = it * 64 + (tid >> 2);
        const int c = (tid & 3) * 8;
        *(s8v*)&As[r][c] = *(const s8v*)(A + (size_t)(m0 + r) * lda + k0 + c);
      }
    }
#pragma unroll
    for (int it = 0; it < BN / 64; ++it) {
      const int r = it * 64 + (tid >> 2);
      const int c = (tid & 3) * 8;
      const int gn = n0 + r;
      s8v v = {0, 0, 0, 0, 0, 0, 0, 0};
      if (gn < N) v = *(const s8v*)(Bt + (size_t)gn * ldb + k0 + c);
      *(s8v*)&Bs[r][c] = v;
    }
    __syncthreads();

    s8v a[FM], b[FN];
#pragma unroll
    for (int i = 0; i < FM; ++i)
      a[i] = *(const s8v*)&As[wm + i * 16 + (lane & 15)][(lane >> 4) * 8];
#pragma unroll
    for (int j = 0; j < FN; ++j)
      b[j] = *(const s8v*)&Bs[wn + j * 16 + (lane & 15)][(lane >> 4) * 8];
#pragma unroll
    for (int i = 0; i < FM; ++i)
#pragma unroll
      for (int j = 0; j < FN; ++j)
        acc[i][j] = __builtin_amdgcn_mfma_f32_16x16x32_bf16(a[i], b[j], acc[i][j], 0, 0, 0);
    __syncthreads();
  }

  const int cr = (lane >> 4) * 4, cc = lane & 15;
#pragma unroll
  for (int i = 0; i < FM; ++i) {
#pragma unroll
    for (int j = 0; j < FN; ++j) {
      const int gn = n0 + wn + j * 16 + cc;
      if (gn >= N) continue;
#pragma unroll
      for (int r = 0; r < 4; ++r) {
        const int gm = m0 + wm + i * 16 + cr + r;
        float v = acc[i][j][r];
        if (bias) v += bias[gn];
        if constexpr (OUT_BF16) ((unsigned short*)Cv)[(size_t)gm * ldc + gn] = f2b(v);
        else                    ((float*)Cv)[(size_t)gm * ldc + gn] = v;
      }
    }
  }
}

// =================== fp32 GEMM (setup-only) ===================
__global__ __launch_bounds__(256)
void gemm_f32(const float* __restrict__ Ap, int lda,
              const float* __restrict__ Bp, int ldb,
              float* __restrict__ Cp, int ldc,
              const float* __restrict__ bias,
              int M, int N, int K)
{
  __shared__ float As[16][64];
  __shared__ float Bs[16][64];
  const int n0 = blockIdx.x * 64;
  const int m0 = blockIdx.y * 64;
  const int tid = threadIdx.x;
  const int tx = tid & 15, ty = tid >> 4;
  float acc[4][4] = {};

  for (int k0 = 0; k0 < K; k0 += 16) {
    {
      const int e = tid << 2;
      const int m = e >> 4;
      const int k = e & 15;
      const int gm = m0 + m, gk = k0 + k;
      float4 v = make_float4(0.f, 0.f, 0.f, 0.f);
      if (gm < M) {
        const float* src = Ap + (size_t)gm * lda + gk;
        if (gk + 3 < K) v = *(const float4*)src;
        else {
          if (gk     < K) v.x = src[0];
          if (gk + 1 < K) v.y = src[1];
          if (gk + 2 < K) v.z = src[2];
          if (gk + 3 < K) v.w = src[3];
        }
      }
      As[k][m] = v.x; As[k + 1][m] = v.y; As[k + 2][m] = v.z; As[k + 3][m] = v.w;
    }
    {
      const int e = tid << 2;
      const int k = e >> 6;
      const int n = e & 63;
      const int gk = k0 + k, gn = n0 + n;
      float4 v = make_float4(0.f, 0.f, 0.f, 0.f);
      if (gk < K) {
        const float* src = Bp + (size_t)gk * ldb + gn;
        if (gn + 3 < N) v = *(const float4*)src;
        else {
          if (gn     < N) v.x = src[0];
          if (gn + 1 < N) v.y = src[1];
          if (gn + 2 < N) v.z = src[2];
          if (gn + 3 < N) v.w = src[3];
        }
      }
      Bs[k][n] = v.x; Bs[k][n + 1] = v.y; Bs[k][n + 2] = v.z; Bs[k][n + 3] = v.w;
    }
    __syncthreads();
#pragma unroll
    for (int k = 0; k < 16; ++k) {
      const float a0 = As[k][ty * 4 + 0], a1 = As[k][ty * 4 + 1];
      const float a2 = As[k][ty * 4 + 2], a3 = As[k][ty * 4 + 3];
      const float b0 = Bs[k][tx * 4 + 0], b1 = Bs[k][tx * 4 + 1];
      const float b2 = Bs[k][tx * 4 + 2], b3 = Bs[k][tx * 4 + 3];
      acc[0][0] += a0 * b0; acc[0][1] += a0 * b1; acc[0][2] += a0 * b2; acc[0][3] += a0 * b3;
      acc[1][0] += a1 * b0; acc[1][1] += a1 * b1; acc[1][2] += a1 * b2; acc[1][3] += a1 * b3;
      acc[2][0] += a2 * b0; acc[2][1] += a2 * b1; acc[2][2] += a2 * b2; acc[2][3] += a2 * b3;
      acc[3][0] += a3 * b0; acc[3][1] += a3 * b1; acc[3][2] += a3 * b2; acc[3][3] += a3 * b3;
    }
    __syncthreads();
  }
#pragma unroll
  for (int i = 0; i < 4; ++i) {
    const int gm = m0 + ty * 4 + i;
    if (gm >= M) continue;
#pragma unroll
    for (int j = 0; j < 4; ++j) {
      const int gn = n0 + tx * 4 + j;
      if (gn >= N) continue;
      float v = acc[i][j];
      if (bias) v += bias[gn];
      Cp[(size_t)gm * ldc + gn] = v;
    }
  }
}

// =================== weight transpose+convert ===================
__global__ void convB_k(const float* __restrict__ src, int srcld, int K, int N,
                        unsigned short* __restrict__ dst, int dstld, int coff, int mode)
{
  __shared__ float t[32][33];
  const int kb = blockIdx.x * 32, nb = blockIdx.y * 32;
  const int tx = threadIdx.x & 31, ty = threadIdx.x >> 5;
#pragma unroll
  for (int i = 0; i < 32; i += 8) {
    const int k = kb + ty + i, n = nb + tx;
    t[ty + i][tx] = (k < K && n < N) ? src[(size_t)k * srcld + n] : 0.f;
  }
  __syncthreads();
#pragma unroll
  for (int i = 0; i < 32; i += 8) {
    const int n = nb + ty + i, k = kb + tx;
    if (n >= N || k >= K) continue;
    const float x = t[tx][ty + i];
    if (mode == 0) {
      const unsigned short h = f2b(x);
      const unsigned short l = f2b(x - b2f(h));
      unsigned short* p = dst + (size_t)n * dstld + coff + 3 * k;
      p[0] = h; p[1] = h; p[2] = l;
    } else {
      dst[(size_t)n * dstld + coff + k] = f2b(x);
    }
  }
}

__global__ void zpad_k(unsigned short* __restrict__ dst, int ld, int c0, int N)
{
  const int w = ld - c0;
  const int idx = blockIdx.x * 256 + threadIdx.x;
  if (idx >= N * w) return;
  dst[(size_t)(idx / w) * ld + c0 + (idx % w)] = 0;
}

// =================== small fused kernels ===================
__global__ void feat_mean_k(const float* __restrict__ feat, float* __restrict__ fm)
{
  const int idx = blockIdx.x * 256 + threadIdx.x;   // NB*VD
  if (idx >= NB * VD) return;
  const int d = idx % VD, b = idx / VD;
  const float* base = feat + (size_t)b * NR * VD + d;
  float s = 0.f;
  for (int r = 0; r < NR; ++r) s += base[(size_t)r * VD];
  fm[idx] = s * (1.f / NR);
}

__global__ void build_x2_k(const int* __restrict__ cap, const float* __restrict__ emb,
                           const float* __restrict__ vinp, unsigned short* __restrict__ X2)
{
  const int idx = blockIdx.x * 256 + threadIdx.x;   // NB*NT*IND
  if (idx >= NB * NT * IND) return;
  const int d = idx % IND;
  const int bt = idx / IND;
  const int t = bt % NT, b = bt / NT;
  float v;
  if (t == 0) v = vinp[b * IND + d];
  else        v = emb[(size_t)cap[b * (NT - 1) + (t - 1)] * IND + d];
  pack3(&X2[(size_t)bt * 900 + 3 * d], v);
}

__global__ void x2step_k(const unsigned short* __restrict__ X2, unsigned short* __restrict__ A2v, int t)
{
  const int idx = blockIdx.x * 256 + threadIdx.x;   // NB*900
  if (idx >= NB * 900) return;
  const int b = idx / 900, c = idx % 900;
  A2v[(size_t)b * KGV + 6144 + c] = X2[((size_t)b * NT + t) * 900 + c];
}

// LSTM-v pointwise: reduce 4 gate partials + FMG(b_v inside); update c_v;
// pack h_v -> A2c@6144 (ha/gates_c) and A2v@3072 (next step W_hh_v)
__global__ void lstm_pw_v_k(const float* __restrict__ gp, const float* __restrict__ fmg,
                            float* __restrict__ cv,
                            unsigned short* __restrict__ A2c, unsigned short* __restrict__ A2v)
{
  const int idx = blockIdx.x * 256 + threadIdx.x;   // NB*NH
  if (idx >= NB * NH) return;
  const int n = idx & (NH - 1), b = idx >> 10;
  const size_t base = (size_t)b * H4;
  float gi = fmg[base + n], gf = fmg[base + NH + n];
  float gg = fmg[base + 2 * NH + n], go = fmg[base + 3 * NH + n];
#pragma unroll
  for (int z = 0; z < ZGV; ++z) {
    const float* g = gp + (size_t)z * NB * H4 + base;
    gi += g[n]; gf += g[NH + n]; gg += g[2 * NH + n]; go += g[3 * NH + n];
  }
  const float c2 = sigm(gf) * cv[idx] + sigm(gi) * tanhf(gg);
  const float h2 = sigm(go) * tanhf(c2);
  cv[idx] = c2;
  unsigned short h = f2b(h2);
  unsigned short l = f2b(h2 - b2f(h));
  unsigned short* p0 = &A2c[(size_t)b * KGC + 6144 + 3 * n];
  unsigned short* p1 = &A2v[(size_t)b * KGV + 3072 + 3 * n];
  p0[0] = h; p0[1] = l; p0[2] = h;
  p1[0] = h; p1[1] = l; p1[2] = h;
}

// LSTM-c pointwise: reduce 4 partials + b_c; update c_c; pack h_c -> A2v@0,
// A2c@9216, OUTH2 row
__global__ void lstm_pw_c_k(const float* __restrict__ gp, const float* __restrict__ bc,
                            float* __restrict__ cc,
                            unsigned short* __restrict__ A2v, unsigned short* __restrict__ A2c,
                            unsigned short* __restrict__ outh2, int t)
{
  const int idx = blockIdx.x * 256 + threadIdx.x;   // NB*NH
  if (idx >= NB * NH) return;
  const int n = idx & (NH - 1), b = idx >> 10;
  const size_t base = (size_t)b * H4;
  float gi = bc[n], gf = bc[NH + n], gg = bc[2 * NH + n], go = bc[3 * NH + n];
#pragma unroll
  for (int z = 0; z < ZGC; ++z) {
    const float* g = gp + (size_t)z * NB * H4 + base;
    gi += g[n]; gf += g[NH + n]; gg += g[2 * NH + n]; go += g[3 * NH + n];
  }
  const float c2 = sigm(gf) * cc[idx] + sigm(gi) * tanhf(gg);
  const float h2 = sigm(go) * tanhf(c2);
  cc[idx] = c2;
  unsigned short h = f2b(h2);
  unsigned short l = f2b(h2 - b2f(h));
  unsigned short* p0 = &A2v[(size_t)b * KGV + 3 * n];
  unsigned short* p1 = &A2c[(size_t)b * KGC + 9216 + 3 * n];
  unsigned short* p2 = &outh2[((size_t)b * NT + t) * KCL + 3 * n];
  p0[0] = h; p0[1] = l; p0[2] = h;
  p1[0] = h; p1[1] = l; p1[2] = h;
  p2[0] = h; p2[1] = l; p2[2] = h;
}

// attention logits: one wave per (b,r); ha = hap0 + hap1 + b_ha
__global__ void att_logits_k(const unsigned short* __restrict__ va16,
                             const float* __restrict__ hap,
                             const float* __restrict__ bha,
                             const float* __restrict__ Wa, const float* __restrict__ ba,
                             float* __restrict__ logits)
{
  const int wave = (blockIdx.x * 256 + threadIdx.x) >> 6;
  const int lane = threadIdx.x & 63;
  if (wave >= NB * NR) return;
  const int b = wave / NR;
  const unsigned short* vrow = va16 + (size_t)wave * NH;
  const float* h0 = hap + (size_t)b * NH;
  const float* h1 = hap + (size_t)NB * NH + (size_t)b * NH;
  float s = 0.f;
  for (int j = lane; j < NH; j += 64)
    s += tanhf(b2f(vrow[j]) + h0[j] + h1[j] + bha[j]) * Wa[j];
  for (int o = 32; o; o >>= 1) s += __shfl_down(s, o);
  if (lane == 0) logits[wave] = s + ba[0];
}

__global__ void att_softmax_k(const float* __restrict__ logits, float* __restrict__ att, int t)
{
  const int b = blockIdx.x;
  const int tx = threadIdx.x;       // 128
  const int lane = tx & 63, wid = tx >> 6;
  __shared__ float red[2];
  float v = (tx < NR) ? logits[b * NR + tx] : -3.4e38f;
  float m = v;
  for (int o = 32; o; o >>= 1) m = fmaxf(m, __shfl_xor(m, o));
  if (lane == 0) red[wid] = m;
  __syncthreads();
  m = fmaxf(red[0], red[1]);
  const float e = (tx < NR) ? expf(v - m) : 0.f;
  float s = e;
  for (int o = 32; o; o >>= 1) s += __shfl_xor(s, o);
  __syncthreads();
  if (lane == 0) red[wid] = s;
  __syncthreads();
  s = red[0] + red[1];
  if (tx < NR) att[(size_t)b * NT * NR + (size_t)t * NR + tx] = e / s;
}

__global__ void feat_hat_k(const float* __restrict__ feat, const float* __restrict__ att,
                           unsigned short* __restrict__ A2c, int t)
{
  const int idx = blockIdx.x * 256 + threadIdx.x;   // NB*VD
  if (idx >= NB * VD) return;
  const int d = idx % VD, b = idx / VD;
  const float* arow = att + (size_t)b * NT * NR + (size_t)t * NR;
  const float* base = feat + (size_t)b * NR * VD + d;
  float s = 0.f;
  for (int r = 0; r < NR; ++r) s += arow[r] * base[(size_t)r * VD];
  pack3(&A2c[(size_t)b * KGC + 3 * d], s * (1.f / NR));
}

inline void gemmF(hipStream_t st, const float* A, int lda, const float* B, int ldb,
                  float* C, int ldc, const float* bias, int M, int N, int K)
{
  dim3 g((N + 63) / 64, (M + 63) / 64);
  gemm_f32<<<g, 256, 0, st>>>(A, lda, B, ldb, C, ldc, bias, M, N, K);
}

inline void convB(hipStream_t st, const float* src, int srcld, int K, int N,
                  unsigned short* dst, int dstld, int coff, int mode)
{
  dim3 g((K + 31) / 32, (N + 31) / 32);
  convB_k<<<g, 256, 0, st>>>(src, srcld, K, N, dst, dstld, coff, mode);
}

} // namespace

extern "C" void kernel_launch(void* const* d_in, const int* in_sizes, int n_in,
                              void* d_out, int out_size, void* d_ws, size_t ws_size,
                              hipStream_t stream)
{
  const int*   caption = (const int*)  d_in[0];
  const float* feat    = (const float*)d_in[1];
  const float* emb     = (const float*)d_in[2];
  const float* W_vin   = (const float*)d_in[3];
  const float* b_vin   = (const float*)d_in[4];
  const float* W_ih_v  = (const float*)d_in[5];   // [3372, 4096]
  const float* W_hh_v  = (const float*)d_in[6];   // [1024, 4096]
  const float* b_v     = (const float*)d_in[7];
  const float* W_va    = (const float*)d_in[8];   // [2048, 1024]
  const float* b_va    = (const float*)d_in[9];
  const float* W_ha    = (const float*)d_in[10];  // [1024, 1024]
  const float* b_ha    = (const float*)d_in[11];
  const float* W_a     = (const float*)d_in[12];  // [1024, 1]
  const float* b_a     = (const float*)d_in[13];
  const float* W_ih_c  = (const float*)d_in[14];  // [3072, 4096]
  const float* W_hh_c  = (const float*)d_in[15];  // [1024, 4096]
  const float* b_c     = (const float*)d_in[16];
  const float* W_cls   = (const float*)d_in[17];  // [1024, 10000]
  const float* b_cls   = (const float*)d_in[18];

  float* out_repr = (float*)d_out;                       // [NB,NT,VOC]
  float* out_att  = out_repr + (size_t)NB * NT * VOC;    // [NB,NT,NR]

  // ---- workspace layout ----
  char* cur = (char*)d_ws;
  auto take = [&](size_t bytes) { char* p = cur; cur += bytes; return p; };

  // zero-region (one memset): A2v, A2c, CV, CC
  unsigned short* A2v  = (unsigned short*)take((size_t)NB * KGV * 2);
  unsigned short* A2c  = (unsigned short*)take((size_t)NB * KGC * 2);
  float* CV            = (float*)take((size_t)NB * NH * 4);
  float* CC            = (float*)take((size_t)NB * NH * 4);
  const size_t ZERO_BYTES = (size_t)NB * KGV * 2 + (size_t)NB * KGC * 2
                          + 2 * (size_t)NB * NH * 4;

  float* FM            = (float*)take((size_t)NB * VD * 4);
  float* VINP          = (float*)take((size_t)NB * IND * 4);
  unsigned short* X2   = (unsigned short*)take((size_t)NB * NT * 900 * 2);
  float* FMG           = (float*)take((size_t)NB * H4 * 4);
  unsigned short* VA16 = (unsigned short*)take((size_t)NB * NR * NH * 2); // 52MB
  float* GP            = (float*)take((size_t)4 * NB * H4 * 4);           // 16.8MB partials
  float* HAP           = (float*)take((size_t)2 * NB * NH * 4);           // 2.1MB partials
  float* LOG           = (float*)take((size_t)NB * NR * 4);
  unsigned short* OUTH2= (unsigned short*)take((size_t)NB * NT * KCL * 2);// 31MB
  unsigned short* Wgv2t= (unsigned short*)take((size_t)H4 * KGV * 2);     // 58MB
  unsigned short* Wha2t= (unsigned short*)take((size_t)NH * KHA * 2);     // 6.3MB
  unsigned short* Wgc2t= (unsigned short*)take((size_t)H4 * KGC * 2);     // 101MB
  unsigned short* Wcls2t=(unsigned short*)take((size_t)VOC * KCL * 2);    // 61MB
  unsigned short* Wva16t=(unsigned short*)take((size_t)NH * VD * 2);      // 4.2MB

  hipMemsetAsync(A2v, 0, ZERO_BYTES, stream);

  // ---- weight conversions ----
  convB(stream, W_ih_v + (size_t)2048 * H4, H4, 1024, H4, Wgv2t, KGV, 0,    0);
  convB(stream, W_hh_v,                     H4, 1024, H4, Wgv2t, KGV, 3072, 0);
  convB(stream, W_ih_v + (size_t)3072 * H4, H4, 300,  H4, Wgv2t, KGV, 6144, 0);
  zpad_k<<<((H4 * (KGV - 7044)) + 255) / 256, 256, 0, stream>>>(Wgv2t, KGV, 7044, H4);
  convB(stream, W_ha, NH, 1024, NH, Wha2t, KHA, 0, 0);
  convB(stream, W_ih_c,                     H4, 2048, H4, Wgc2t, KGC, 0,    0);
  convB(stream, W_ih_c + (size_t)2048 * H4, H4, 1024, H4, Wgc2t, KGC, 6144, 0);
  convB(stream, W_hh_c,                     H4, 1024, H4, Wgc2t, KGC, 9216, 0);
  convB(stream, W_cls, VOC, 1024, VOC, Wcls2t, KCL, 0, 0);
  convB(stream, W_va, NH, VD, NH, Wva16t, VD, 0, 1);

  // ---- setup ----
  feat_mean_k<<<(NB * VD + 255) / 256, 256, 0, stream>>>(feat, FM);
  gemmF(stream, FM, VD, W_vin, IND, VINP, IND, b_vin, NB, IND, VD);
  build_x2_k<<<(NB * NT * IND + 255) / 256, 256, 0, stream>>>(caption, emb, VINP, X2);
  gemmF(stream, FM, VD, W_ih_v, H4, FMG, H4, b_v, NB, H4, VD);
  // VA16 = bf16(features @ W_va + b_va), m-inner grid for L2 reuse
  {
    dim3 g((NB * NR) / 128, NH / 128);
    gemm_mfma<128, 128, true, true, true><<<g, 256, 0, stream>>>(
        feat, VD, Wva16t, VD, VA16, NH, b_va, NB * NR, NH, VD);
  }

  // ---- sequential decode ----
  for (int t = 0; t < NT; ++t) {
    x2step_k<<<(NB * 900 + 255) / 256, 256, 0, stream>>>(X2, A2v, t);
    // gates_v partials = [h_c|h_v|x_t] @ Wgv  (4-way split-K)
    gemm_sk<<<dim3(H4 / 64, NB / 64, ZGV), 256, 0, stream>>>(
        A2v, KGV, Wgv2t, KGV, GP, NB, H4, KGV, KSV);
    lstm_pw_v_k<<<(NB * NH + 255) / 256, 256, 0, stream>>>(GP, FMG, CV, A2c, A2v);
    // ha partials = h_v @ W_ha  (2-way split-K)
    gemm_sk<<<dim3(NH / 64, NB / 64, ZHA), 256, 0, stream>>>(
        A2c + 6144, KGC, Wha2t, KHA, HAP, NB, NH, KHA, KSH);
    att_logits_k<<<(NB * NR * 64 + 255) / 256, 256, 0, stream>>>(
        VA16, HAP, b_ha, W_a, b_a, LOG);
    att_softmax_k<<<NB, 128, 0, stream>>>(LOG, out_att, t);
    feat_hat_k<<<(NB * VD + 255) / 256, 256, 0, stream>>>(feat, out_att, A2c, t);
    // gates_c partials = [feat_hat|h_v|h_c] @ Wgc  (4-way split-K)
    gemm_sk<<<dim3(H4 / 64, NB / 64, ZGC), 256, 0, stream>>>(
        A2c, KGC, Wgc2t, KGC, GP, NB, H4, KGC, KSC);
    lstm_pw_c_k<<<(NB * NH + 255) / 256, 256, 0, stream>>>(GP, b_c, CC, A2v, A2c, OUTH2, t);
  }

  // ---- classifier: out = OUTH2 @ W_cls + b_cls (m-inner grid) ----
  {
    dim3 g((NB * NT) / 128, (VOC + 127) / 128);
    gemm_mfma<128, 128, false, false, true><<<g, 256, 0, stream>>>(
        OUTH2, KCL, Wcls2t, KCL, out_repr, VOC, b_cls, NB * NT, VOC, KCL);
  }
}

// Round 5
// 6013.884 us; speedup vs baseline: 3.2011x; 1.2379x over previous
//
#include <hip/hip_runtime.h>
#include <math.h>

namespace {

constexpr int NB  = 256;    // batch
constexpr int NT  = 20;     // time steps
constexpr int NR  = 100;    // regions
constexpr int IND = 300;    // in_dim
constexpr int NH  = 1024;   // num_hid
constexpr int VD  = 2048;   // v_dim
constexpr int H4  = 4096;   // 4*num_hid
constexpr int VOC = 10000;  // vocab
constexpr int VOCP= 10112;  // vocab padded to 128

// packed K' layout: per original k, 3 slots. A side: [hi, lo, hi]; B side: [hi, hi, lo]
constexpr int KGV = 7072;   // gates_v K' : 3*(1024+1024+300)=7044 -> pad 7072
constexpr int KGC = 12288;  // gates_c K' : 3*(2048+1024+1024)
constexpr int KHA = 3072;   // ha K'
constexpr int KCL = 3072;   // cls K'
constexpr int A2VLD = 6144; // A2v row: [h_c(3072) | h_v(3072)]; x-seg read from X2
constexpr int X2LD  = 928;  // 900 packed + 28 zero pad (16B-aligned rows)

// split-K: 8-way -> 2048 blocks = 8 blocks/CU (latency hiding via TLP)
constexpr int ZGV = 8; constexpr int KSV = 896;    // 8*896 >= 7072
constexpr int ZGC = 8; constexpr int KSC = 1536;
constexpr int ZHA = 8; constexpr int KSH = 384;

typedef short  s8v  __attribute__((ext_vector_type(8)));
typedef float  f4v  __attribute__((ext_vector_type(4)));

__device__ __forceinline__ float sigm(float x) { return 1.f / (1.f + expf(-x)); }

__device__ __forceinline__ unsigned short f2b(float x) {
  return __builtin_bit_cast(unsigned short, (__bf16)x);
}
__device__ __forceinline__ float b2f(unsigned short u) {
  return (float)__builtin_bit_cast(__bf16, u);
}
__device__ __forceinline__ void pack3(unsigned short* p, float x) {
  unsigned short h = f2b(x);
  unsigned short l = f2b(x - b2f(h));
  p[0] = h; p[1] = l; p[2] = h;
}

// async global->LDS, 16B per lane. LDS dest must be linear in lane order.
__device__ __forceinline__ void gload16(const unsigned short* g, unsigned short* l) {
  __builtin_amdgcn_global_load_lds(
      (const __attribute__((address_space(1))) void*)g,
      (__attribute__((address_space(3))) void*)l, 16, 0, 0);
}

// =================== split-K bf16 MFMA GEMM (skinny M), gload staging ===========
// A [M,lda] bf16; XSEG: k>=A2VLD read from X2[(row*NT+t)*X2LD + (k-A2VLD)].
// Bt [N,ldb] bf16 (pre-transposed). Partial z -> P + z*M*N (fp32).
template<bool XSEG>
__global__ __launch_bounds__(256)
void gemm_sk(const unsigned short* __restrict__ A, int lda,
             const unsigned short* __restrict__ X2, int t,
             const unsigned short* __restrict__ Bt, int ldb,
             float* __restrict__ P, int M, int N, int Kp, int Ksplit)
{
  __shared__ unsigned short As[64 * 32];
  __shared__ unsigned short Bs[64 * 32];
  const int tid = threadIdx.x, wid = tid >> 6, lane = tid & 63;
  const int wm = (wid >> 1) * 32, wn = (wid & 1) * 32;
  const int m0 = blockIdx.y * 64, n0 = blockIdx.x * 64;
  const int kbeg = blockIdx.z * Ksplit;
  const int kend = min(Kp, kbeg + Ksplit);
  const int sr = tid >> 2, sc = (tid & 3) * 8;
  unsigned short* ad = &As[tid * 8];
  unsigned short* bd = &Bs[tid * 8];
  const unsigned short* asrc = A + (size_t)(m0 + sr) * lda + sc;
  const unsigned short* xsrc = nullptr;
  if constexpr (XSEG) xsrc = X2 + ((size_t)(m0 + sr) * NT + t) * X2LD + sc;
  const unsigned short* bsrc = Bt + (size_t)(n0 + sr) * ldb + sc;

  f4v acc[2][2] = {};
  for (int k0 = kbeg; k0 < kend; k0 += 32) {
    if constexpr (XSEG) {
      if (k0 >= A2VLD) gload16(xsrc + (k0 - A2VLD), ad);
      else             gload16(asrc + k0, ad);
    } else {
      gload16(asrc + k0, ad);
    }
    gload16(bsrc + k0, bd);
    __syncthreads();
    const int rr = lane & 15, kc = (lane >> 4) * 8;
    s8v a0 = *(const s8v*)&As[(wm + rr) * 32 + kc];
    s8v a1 = *(const s8v*)&As[(wm + 16 + rr) * 32 + kc];
    s8v b0 = *(const s8v*)&Bs[(wn + rr) * 32 + kc];
    s8v b1 = *(const s8v*)&Bs[(wn + 16 + rr) * 32 + kc];
    acc[0][0] = __builtin_amdgcn_mfma_f32_16x16x32_bf16(a0, b0, acc[0][0], 0, 0, 0);
    acc[0][1] = __builtin_amdgcn_mfma_f32_16x16x32_bf16(a0, b1, acc[0][1], 0, 0, 0);
    acc[1][0] = __builtin_amdgcn_mfma_f32_16x16x32_bf16(a1, b0, acc[1][0], 0, 0, 0);
    acc[1][1] = __builtin_amdgcn_mfma_f32_16x16x32_bf16(a1, b1, acc[1][1], 0, 0, 0);
    __syncthreads();
  }

  float* out = P + (size_t)blockIdx.z * M * N;
  const int cr = (lane >> 4) * 4, cc = lane & 15;
#pragma unroll
  for (int i = 0; i < 2; ++i)
#pragma unroll
    for (int j = 0; j < 2; ++j)
#pragma unroll
      for (int r = 0; r < 4; ++r)
        out[(size_t)(m0 + wm + i * 16 + cr + r) * N + n0 + wn + j * 16 + cc] = acc[i][j][r];
}

// =================== 128x128 bf16 MFMA GEMM, m-inner grid, gload staging ========
// grid: x = M/128 (inner), y = N-tiles (B rows must exist for full y*128 range).
template<bool A_F32, bool OUT_BF16>
__global__ __launch_bounds__(256)
void gemm_mfma(const void* __restrict__ Av, int lda,
               const unsigned short* __restrict__ Bt, int ldb,
               void* __restrict__ Cv, int ldc,
               const float* __restrict__ bias,
               int M, int N, int Kp)
{
  __shared__ unsigned short As[128 * 32];
  __shared__ unsigned short Bs[128 * 32];
  const int tid = threadIdx.x, wid = tid >> 6, lane = tid & 63;
  const int wm = (wid >> 1) * 64, wn = (wid & 1) * 64;
  const int m0 = blockIdx.x * 128, n0 = blockIdx.y * 128;

  const unsigned short* bsrc0 = Bt + (size_t)(n0 + (tid >> 2)) * ldb + (tid & 3) * 8;
  const unsigned short* bsrc1 = bsrc0 + (size_t)64 * ldb;
  unsigned short* bd0 = &Bs[tid * 8];
  unsigned short* bd1 = &Bs[2048 + tid * 8];
  const unsigned short* asrc0 = nullptr;
  const unsigned short* asrc1 = nullptr;
  unsigned short* ad0 = &As[tid * 8];
  unsigned short* ad1 = &As[2048 + tid * 8];
  if constexpr (!A_F32) {
    const unsigned short* A = (const unsigned short*)Av;
    asrc0 = A + (size_t)(m0 + (tid >> 2)) * lda + (tid & 3) * 8;
    asrc1 = asrc0 + (size_t)64 * lda;
  }

  f4v acc[4][4] = {};
  for (int k0 = 0; k0 < Kp; k0 += 32) {
    if constexpr (A_F32) {
      const float* A = (const float*)Av;
#pragma unroll
      for (int it = 0; it < 4; ++it) {
        const int r = it * 32 + (tid >> 3), c = (tid & 7) * 4;
        const float4 v = *(const float4*)(A + (size_t)(m0 + r) * lda + k0 + c);
        ushort4 w;
        w.x = f2b(v.x); w.y = f2b(v.y); w.z = f2b(v.z); w.w = f2b(v.w);
        *(ushort4*)&As[r * 32 + c] = w;
      }
    } else {
      gload16(asrc0 + k0, ad0);
      gload16(asrc1 + k0, ad1);
    }
    gload16(bsrc0 + k0, bd0);
    gload16(bsrc1 + k0, bd1);
    __syncthreads();

    const int rr = lane & 15, kc = (lane >> 4) * 8;
    s8v a[4], b[4];
#pragma unroll
    for (int i = 0; i < 4; ++i) a[i] = *(const s8v*)&As[(wm + i * 16 + rr) * 32 + kc];
#pragma unroll
    for (int j = 0; j < 4; ++j) b[j] = *(const s8v*)&Bs[(wn + j * 16 + rr) * 32 + kc];
#pragma unroll
    for (int i = 0; i < 4; ++i)
#pragma unroll
      for (int j = 0; j < 4; ++j)
        acc[i][j] = __builtin_amdgcn_mfma_f32_16x16x32_bf16(a[i], b[j], acc[i][j], 0, 0, 0);
    __syncthreads();
  }

  const int cr = (lane >> 4) * 4, cc = lane & 15;
#pragma unroll
  for (int i = 0; i < 4; ++i) {
#pragma unroll
    for (int j = 0; j < 4; ++j) {
      const int gn = n0 + wn + j * 16 + cc;
      if (gn >= N) continue;
#pragma unroll
      for (int r = 0; r < 4; ++r) {
        const int gm = m0 + wm + i * 16 + cr + r;
        float v = acc[i][j][r];
        if (bias) v += bias[gn];
        if constexpr (OUT_BF16) ((unsigned short*)Cv)[(size_t)gm * ldc + gn] = f2b(v);
        else                    ((float*)Cv)[(size_t)gm * ldc + gn] = v;
      }
    }
  }
}

// =================== fp32 GEMM (setup-only, small) ===================
__global__ __launch_bounds__(256)
void gemm_f32(const float* __restrict__ Ap, int lda,
              const float* __restrict__ Bp, int ldb,
              float* __restrict__ Cp, int ldc,
              const float* __restrict__ bias,
              int M, int N, int K)
{
  __shared__ float As[16][64];
  __shared__ float Bs[16][64];
  const int n0 = blockIdx.x * 64;
  const int m0 = blockIdx.y * 64;
  const int tid = threadIdx.x;
  const int tx = tid & 15, ty = tid >> 4;
  float acc[4][4] = {};

  for (int k0 = 0; k0 < K; k0 += 16) {
    {
      const int e = tid << 2;
      const int m = e >> 4, k = e & 15;
      const int gm = m0 + m, gk = k0 + k;
      float4 v = make_float4(0.f, 0.f, 0.f, 0.f);
      if (gm < M) {
        const float* src = Ap + (size_t)gm * lda + gk;
        if (gk + 3 < K) v = *(const float4*)src;
        else {
          if (gk     < K) v.x = src[0];
          if (gk + 1 < K) v.y = src[1];
          if (gk + 2 < K) v.z = src[2];
          if (gk + 3 < K) v.w = src[3];
        }
      }
      As[k][m] = v.x; As[k + 1][m] = v.y; As[k + 2][m] = v.z; As[k + 3][m] = v.w;
    }
    {
      const int e = tid << 2;
      const int k = e >> 6, n = e & 63;
      const int gk = k0 + k, gn = n0 + n;
      float4 v = make_float4(0.f, 0.f, 0.f, 0.f);
      if (gk < K) {
        const float* src = Bp + (size_t)gk * ldb + gn;
        if (gn + 3 < N) v = *(const float4*)src;
        else {
          if (gn     < N) v.x = src[0];
          if (gn + 1 < N) v.y = src[1];
          if (gn + 2 < N) v.z = src[2];
          if (gn + 3 < N) v.w = src[3];
        }
      }
      Bs[k][n] = v.x; Bs[k][n + 1] = v.y; Bs[k][n + 2] = v.z; Bs[k][n + 3] = v.w;
    }
    __syncthreads();
#pragma unroll
    for (int k = 0; k < 16; ++k) {
      const float a0 = As[k][ty * 4 + 0], a1 = As[k][ty * 4 + 1];
      const float a2 = As[k][ty * 4 + 2], a3 = As[k][ty * 4 + 3];
      const float b0 = Bs[k][tx * 4 + 0], b1 = Bs[k][tx * 4 + 1];
      const float b2 = Bs[k][tx * 4 + 2], b3 = Bs[k][tx * 4 + 3];
      acc[0][0] += a0 * b0; acc[0][1] += a0 * b1; acc[0][2] += a0 * b2; acc[0][3] += a0 * b3;
      acc[1][0] += a1 * b0; acc[1][1] += a1 * b1; acc[1][2] += a1 * b2; acc[1][3] += a1 * b3;
      acc[2][0] += a2 * b0; acc[2][1] += a2 * b1; acc[2][2] += a2 * b2; acc[2][3] += a2 * b3;
      acc[3][0] += a3 * b0; acc[3][1] += a3 * b1; acc[3][2] += a3 * b2; acc[3][3] += a3 * b3;
    }
    __syncthreads();
  }
#pragma unroll
  for (int i = 0; i < 4; ++i) {
    const int gm = m0 + ty * 4 + i;
    if (gm >= M) continue;
#pragma unroll
    for (int j = 0; j < 4; ++j) {
      const int gn = n0 + tx * 4 + j;
      if (gn >= N) continue;
      float v = acc[i][j];
      if (bias) v += bias[gn];
      Cp[(size_t)gm * ldc + gn] = v;
    }
  }
}

// =================== weight transpose+convert ===================
__global__ void convB_k(const float* __restrict__ src, int srcld, int K, int N,
                        unsigned short* __restrict__ dst, int dstld, int coff, int mode)
{
  __shared__ float t[32][33];
  const int kb = blockIdx.x * 32, nb = blockIdx.y * 32;
  const int tx = threadIdx.x & 31, ty = threadIdx.x >> 5;
#pragma unroll
  for (int i = 0; i < 32; i += 8) {
    const int k = kb + ty + i, n = nb + tx;
    t[ty + i][tx] = (k < K && n < N) ? src[(size_t)k * srcld + n] : 0.f;
  }
  __syncthreads();
#pragma unroll
  for (int i = 0; i < 32; i += 8) {
    const int n = nb + ty + i, k = kb + tx;
    if (n >= N || k >= K) continue;
    const float x = t[tx][ty + i];
    if (mode == 0) {
      const unsigned short h = f2b(x);
      const unsigned short l = f2b(x - b2f(h));
      unsigned short* p = dst + (size_t)n * dstld + coff + 3 * k;
      p[0] = h; p[1] = h; p[2] = l;
    } else {
      dst[(size_t)n * dstld + coff + k] = f2b(x);
    }
  }
}

__global__ void zpad_k(unsigned short* __restrict__ dst, int ld, int c0, int N)
{
  const int w = ld - c0;
  const int idx = blockIdx.x * 256 + threadIdx.x;
  if (idx >= N * w) return;
  dst[(size_t)(idx / w) * ld + c0 + (idx % w)] = 0;
}

__global__ void zfill_k(unsigned short* __restrict__ p, int n)
{
  const int i = blockIdx.x * 256 + threadIdx.x;
  if (i < n) p[i] = 0;
}

// =================== small kernels ===================
__global__ void feat_mean_k(const float* __restrict__ feat, float* __restrict__ fm)
{
  const int idx = blockIdx.x * 256 + threadIdx.x;   // NB*VD
  if (idx >= NB * VD) return;
  const int d = idx % VD, b = idx / VD;
  const float* base = feat + (size_t)b * NR * VD + d;
  float s = 0.f;
  for (int r = 0; r < NR; ++r) s += base[(size_t)r * VD];
  fm[idx] = s * (1.f / NR);
}

// features f32 -> bf16 (hi), 8 elems/thread, grid-stride
__global__ void f2b8_k(const float* __restrict__ in, unsigned short* __restrict__ out, long n8)
{
  for (long i = blockIdx.x * 256 + threadIdx.x; i < n8; i += (long)gridDim.x * 256) {
    const float4 a = *(const float4*)(in + i * 8);
    const float4 b = *(const float4*)(in + i * 8 + 4);
    unsigned short w[8] = {f2b(a.x), f2b(a.y), f2b(a.z), f2b(a.w),
                           f2b(b.x), f2b(b.y), f2b(b.z), f2b(b.w)};
    *(s8v*)(out + i * 8) = *(const s8v*)w;
  }
}

// X2[(b*NT+t)*X2LD + c]: c<900 packed x_t slots, c>=900 zero
__global__ void build_x2_k(const int* __restrict__ cap, const float* __restrict__ emb,
                           const float* __restrict__ vinp, unsigned short* __restrict__ X2)
{
  const int idx = blockIdx.x * 256 + threadIdx.x;   // NB*NT*X2LD
  if (idx >= NB * NT * X2LD) return;
  const int c = idx % X2LD;
  const int bt = idx / X2LD;
  if (c >= 900) { X2[idx] = 0; return; }
  const int t = bt % NT, b = bt / NT;
  const int d = c / 3, s = c % 3;
  const float v = (t == 0) ? vinp[b * IND + d]
                           : emb[(size_t)cap[b * (NT - 1) + (t - 1)] * IND + d];
  const unsigned short h = f2b(v);
  X2[idx] = (s == 1) ? f2b(v - b2f(h)) : h;
}

// LSTM-v pointwise: reduce ZGV partials + FMG(b_v inside); update c_v;
// pack h_v -> A2c@6144 and A2v@3072 (next step W_hh_v term)
__global__ void lstm_pw_v_k(const float* __restrict__ gp, const float* __restrict__ fmg,
                            float* __restrict__ cv,
                            unsigned short* __restrict__ A2c, unsigned short* __restrict__ A2v)
{
  const int idx = blockIdx.x * 256 + threadIdx.x;   // NB*NH
  if (idx >= NB * NH) return;
  const int n = idx & (NH - 1), b = idx >> 10;
  const size_t base = (size_t)b * H4;
  float gi = fmg[base + n], gf = fmg[base + NH + n];
  float gg = fmg[base + 2 * NH + n], go = fmg[base + 3 * NH + n];
#pragma unroll
  for (int z = 0; z < ZGV; ++z) {
    const float* g = gp + (size_t)z * NB * H4 + base;
    gi += g[n]; gf += g[NH + n]; gg += g[2 * NH + n]; go += g[3 * NH + n];
  }
  const float c2 = sigm(gf) * cv[idx] + sigm(gi) * tanhf(gg);
  const float h2 = sigm(go) * tanhf(c2);
  cv[idx] = c2;
  const unsigned short h = f2b(h2);
  const unsigned short l = f2b(h2 - b2f(h));
  unsigned short* p0 = &A2c[(size_t)b * KGC + 6144 + 3 * n];
  unsigned short* p1 = &A2v[(size_t)b * A2VLD + 3072 + 3 * n];
  p0[0] = h; p0[1] = l; p0[2] = h;
  p1[0] = h; p1[1] = l; p1[2] = h;
}

// LSTM-c pointwise: reduce ZGC partials + b_c; update c_c;
// pack h_c -> A2v@0, A2c@9216, OUTH2 row
__global__ void lstm_pw_c_k(const float* __restrict__ gp, const float* __restrict__ bc,
                            float* __restrict__ cc,
                            unsigned short* __restrict__ A2v, unsigned short* __restrict__ A2c,
                            unsigned short* __restrict__ outh2, int t)
{
  const int idx = blockIdx.x * 256 + threadIdx.x;   // NB*NH
  if (idx >= NB * NH) return;
  const int n = idx & (NH - 1), b = idx >> 10;
  const size_t base = (size_t)b * H4;
  float gi = bc[n], gf = bc[NH + n], gg = bc[2 * NH + n], go = bc[3 * NH + n];
#pragma unroll
  for (int z = 0; z < ZGC; ++z) {
    const float* g = gp + (size_t)z * NB * H4 + base;
    gi += g[n]; gf += g[NH + n]; gg += g[2 * NH + n]; go += g[3 * NH + n];
  }
  const float c2 = sigm(gf) * cc[idx] + sigm(gi) * tanhf(gg);
  const float h2 = sigm(go) * tanhf(c2);
  cc[idx] = c2;
  const unsigned short h = f2b(h2);
  const unsigned short l = f2b(h2 - b2f(h));
  unsigned short* p0 = &A2v[(size_t)b * A2VLD + 3 * n];
  unsigned short* p1 = &A2c[(size_t)b * KGC + 9216 + 3 * n];
  unsigned short* p2 = &outh2[((size_t)b * NT + t) * KCL + 3 * n];
  p0[0] = h; p0[1] = l; p0[2] = h;
  p1[0] = h; p1[1] = l; p1[2] = h;
  p2[0] = h; p2[1] = l; p2[2] = h;
}

// =================== fused attention: logits + softmax + feat_hat ===============
// one block per b (256 threads). F16: features as bf16; else fp32.
template<bool F16>
__global__ __launch_bounds__(256)
void att_fused_k(const unsigned short* __restrict__ va16,
                 const float* __restrict__ hap,       // [ZHA][NB][NH]
                 const float* __restrict__ bha,
                 const float* __restrict__ Wa, const float* __restrict__ ba,
                 const unsigned short* __restrict__ f16,
                 const float* __restrict__ f32,
                 unsigned short* __restrict__ A2c,
                 float* __restrict__ att_out, int t)
{
  const int b = blockIdx.x, tid = threadIdx.x;
  const int lane = tid & 63, wid = tid >> 6;
  __shared__ float ha_s[NH];
  __shared__ float wa_s[NH];
  __shared__ float red_s[128];

  for (int j = tid; j < NH; j += 256) {
    float s = bha[j];
#pragma unroll
    for (int z = 0; z < ZHA; ++z) s += hap[((size_t)z * NB + b) * NH + j];
    ha_s[j] = s;
    wa_s[j] = Wa[j];
  }
  __syncthreads();

  // logits: wave w handles regions w, w+4, ... (25 each); lane covers 16 j's
  for (int r = wid; r < NR; r += 4) {
    const unsigned short* vrow = va16 + ((size_t)b * NR + r) * NH + lane * 16;
    float s = 0.f;
#pragma unroll
    for (int u = 0; u < 2; ++u) {
      const s8v v = *(const s8v*)(vrow + u * 8);
      const int j0 = lane * 16 + u * 8;
#pragma unroll
      for (int e = 0; e < 8; ++e)
        s += tanhf(b2f((unsigned short)v[e]) + ha_s[j0 + e]) * wa_s[j0 + e];
    }
    for (int o = 32; o; o >>= 1) s += __shfl_down(s, o);
    if (lane == 0) red_s[r] = s + ba[0];
  }
  __syncthreads();

  // softmax over 100 regions (wave 0)
  if (wid == 0) {
    float v0 = (lane < NR) ? red_s[lane] : -3.4e38f;
    float v1 = (lane + 64 < NR) ? red_s[lane + 64] : -3.4e38f;
    float m = fmaxf(v0, v1);
    for (int o = 32; o; o >>= 1) m = fmaxf(m, __shfl_xor(m, o));
    const float e0 = (lane < NR) ? expf(v0 - m) : 0.f;
    const float e1 = (lane + 64 < NR) ? expf(v1 - m) : 0.f;
    float s = e0 + e1;
    for (int o = 32; o; o >>= 1) s += __shfl_xor(s, o);
    const float inv = 1.f / s;
    if (lane < NR) red_s[lane] = e0 * inv;
    if (lane + 64 < NR) red_s[lane + 64] = e1 * inv;
  }
  __syncthreads();

  if (tid < NR) att_out[((size_t)b * NT + t) * NR + tid] = red_s[tid];

  // feat_hat: thread handles 8 consecutive d
  const int d0 = tid * 8;
  float fh[8] = {};
  if constexpr (F16) {
    const unsigned short* fb = f16 + (size_t)b * NR * VD + d0;
    for (int r = 0; r < NR; ++r) {
      const s8v f = *(const s8v*)(fb + (size_t)r * VD);
      const float a = red_s[r];
#pragma unroll
      for (int e = 0; e < 8; ++e) fh[e] += a * b2f((unsigned short)f[e]);
    }
  } else {
    const float* fb = f32 + (size_t)b * NR * VD + d0;
    for (int r = 0; r < NR; ++r) {
      const float4 x0 = *(const float4*)(fb + (size_t)r * VD);
      const float4 x1 = *(const float4*)(fb + (size_t)r * VD + 4);
      const float a = red_s[r];
      fh[0] += a * x0.x; fh[1] += a * x0.y; fh[2] += a * x0.z; fh[3] += a * x0.w;
      fh[4] += a * x1.x; fh[5] += a * x1.y; fh[6] += a * x1.z; fh[7] += a * x1.w;
    }
  }
  unsigned short* dst = &A2c[(size_t)b * KGC + 3 * d0];
#pragma unroll
  for (int e = 0; e < 8; ++e) pack3(dst + 3 * e, fh[e] * (1.f / NR));
}

inline void gemmF(hipStream_t st, const float* A, int lda, const float* B, int ldb,
                  float* C, int ldc, const float* bias, int M, int N, int K)
{
  dim3 g((N + 63) / 64, (M + 63) / 64);
  gemm_f32<<<g, 256, 0, st>>>(A, lda, B, ldb, C, ldc, bias, M, N, K);
}

inline void convB(hipStream_t st, const float* src, int srcld, int K, int N,
                  unsigned short* dst, int dstld, int coff, int mode)
{
  dim3 g((K + 31) / 32, (N + 31) / 32);
  convB_k<<<g, 256, 0, st>>>(src, srcld, K, N, dst, dstld, coff, mode);
}

} // namespace

extern "C" void kernel_launch(void* const* d_in, const int* in_sizes, int n_in,
                              void* d_out, int out_size, void* d_ws, size_t ws_size,
                              hipStream_t stream)
{
  const int*   caption = (const int*)  d_in[0];
  const float* feat    = (const float*)d_in[1];
  const float* emb     = (const float*)d_in[2];
  const float* W_vin   = (const float*)d_in[3];
  const float* b_vin   = (const float*)d_in[4];
  const float* W_ih_v  = (const float*)d_in[5];   // [3372, 4096]
  const float* W_hh_v  = (const float*)d_in[6];   // [1024, 4096]
  const float* b_v     = (const float*)d_in[7];
  const float* W_va    = (const float*)d_in[8];   // [2048, 1024]
  const float* b_va    = (const float*)d_in[9];
  const float* W_ha    = (const float*)d_in[10];  // [1024, 1024]
  const float* b_ha    = (const float*)d_in[11];
  const float* W_a     = (const float*)d_in[12];  // [1024, 1]
  const float* b_a     = (const float*)d_in[13];
  const float* W_ih_c  = (const float*)d_in[14];  // [3072, 4096]
  const float* W_hh_c  = (const float*)d_in[15];  // [1024, 4096]
  const float* b_c     = (const float*)d_in[16];
  const float* W_cls   = (const float*)d_in[17];  // [1024, 10000]
  const float* b_cls   = (const float*)d_in[18];

  float* out_repr = (float*)d_out;                       // [NB,NT,VOC]
  float* out_att  = out_repr + (size_t)NB * NT * VOC;    // [NB,NT,NR]

  // ---- workspace layout ----
  char* cur = (char*)d_ws;
  auto take = [&](size_t bytes) { char* p = cur; cur += bytes; return p; };

  // zero-region (one memset): A2v, A2c, CV, CC
  unsigned short* A2v  = (unsigned short*)take((size_t)NB * A2VLD * 2);   // 3.1MB
  unsigned short* A2c  = (unsigned short*)take((size_t)NB * KGC * 2);     // 6.3MB
  float* CV            = (float*)take((size_t)NB * NH * 4);
  float* CC            = (float*)take((size_t)NB * NH * 4);
  const size_t ZERO_BYTES = (size_t)NB * A2VLD * 2 + (size_t)NB * KGC * 2
                          + 2 * (size_t)NB * NH * 4;

  float* FM            = (float*)take((size_t)NB * VD * 4);
  float* VINP          = (float*)take((size_t)NB * IND * 4);
  unsigned short* X2   = (unsigned short*)take((size_t)NB * NT * X2LD * 2); // 9.5MB
  float* FMG           = (float*)take((size_t)NB * H4 * 4);
  unsigned short* VA16 = (unsigned short*)take((size_t)NB * NR * NH * 2);   // 52MB
  float* GP            = (float*)take((size_t)ZGC * NB * H4 * 4);           // 33.5MB
  float* HAP           = (float*)take((size_t)ZHA * NB * NH * 4);           // 8.4MB
  unsigned short* OUTH2= (unsigned short*)take((size_t)NB * NT * KCL * 2);  // 31.5MB
  unsigned short* Wgv2t= (unsigned short*)take((size_t)H4 * KGV * 2);       // 58MB
  unsigned short* Wha2t= (unsigned short*)take((size_t)NH * KHA * 2);       // 6.3MB
  unsigned short* Wgc2t= (unsigned short*)take((size_t)H4 * KGC * 2);       // 101MB
  unsigned short* Wcls2t=(unsigned short*)take((size_t)VOCP * KCL * 2);     // 62MB
  unsigned short* Wva16t=(unsigned short*)take((size_t)NH * VD * 2);        // 4.2MB
  unsigned short* FEAT16=(unsigned short*)cur;                              // 105MB (optional)
  const bool useF16 = ((size_t)(cur - (char*)d_ws) + (size_t)NB * NR * VD * 2) <= ws_size;

  hipMemsetAsync(A2v, 0, ZERO_BYTES, stream);

  // ---- weight conversions ----
  convB(stream, W_ih_v + (size_t)2048 * H4, H4, 1024, H4, Wgv2t, KGV, 0,    0);
  convB(stream, W_hh_v,                     H4, 1024, H4, Wgv2t, KGV, 3072, 0);
  convB(stream, W_ih_v + (size_t)3072 * H4, H4, 300,  H4, Wgv2t, KGV, 6144, 0);
  zpad_k<<<((H4 * (KGV - 7044)) + 255) / 256, 256, 0, stream>>>(Wgv2t, KGV, 7044, H4);
  convB(stream, W_ha, NH, 1024, NH, Wha2t, KHA, 0, 0);
  convB(stream, W_ih_c,                     H4, 2048, H4, Wgc2t, KGC, 0,    0);
  convB(stream, W_ih_c + (size_t)2048 * H4, H4, 1024, H4, Wgc2t, KGC, 6144, 0);
  convB(stream, W_hh_c,                     H4, 1024, H4, Wgc2t, KGC, 9216, 0);
  convB(stream, W_cls, VOC, 1024, VOC, Wcls2t, KCL, 0, 0);
  zfill_k<<<(((VOCP - VOC) * KCL) + 255) / 256, 256, 0, stream>>>(
      Wcls2t + (size_t)VOC * KCL, (VOCP - VOC) * KCL);
  convB(stream, W_va, NH, VD, NH, Wva16t, VD, 0, 1);

  // ---- setup ----
  feat_mean_k<<<(NB * VD + 255) / 256, 256, 0, stream>>>(feat, FM);
  gemmF(stream, FM, VD, W_vin, IND, VINP, IND, b_vin, NB, IND, VD);
  build_x2_k<<<(NB * NT * X2LD + 255) / 256, 256, 0, stream>>>(caption, emb, VINP, X2);
  gemmF(stream, FM, VD, W_ih_v, H4, FMG, H4, b_v, NB, H4, VD);
  if (useF16) {
    f2b8_k<<<2048, 256, 0, stream>>>(feat, FEAT16, (long)NB * NR * VD / 8);
    dim3 g((NB * NR) / 128, NH / 128);
    gemm_mfma<false, true><<<g, 256, 0, stream>>>(
        FEAT16, VD, Wva16t, VD, VA16, NH, b_va, NB * NR, NH, VD);
  } else {
    dim3 g((NB * NR) / 128, NH / 128);
    gemm_mfma<true, true><<<g, 256, 0, stream>>>(
        feat, VD, Wva16t, VD, VA16, NH, b_va, NB * NR, NH, VD);
  }

  // ---- sequential decode ----
  for (int t = 0; t < NT; ++t) {
    // gates_v partials = [h_c|h_v|x_t] @ Wgv  (8-way split-K; x from X2)
    gemm_sk<true><<<dim3(H4 / 64, NB / 64, ZGV), 256, 0, stream>>>(
        A2v, A2VLD, X2, t, Wgv2t, KGV, GP, NB, H4, KGV, KSV);
    lstm_pw_v_k<<<(NB * NH + 255) / 256, 256, 0, stream>>>(GP, FMG, CV, A2c, A2v);
    // ha partials = h_v @ W_ha  (8-way split-K)
    gemm_sk<false><<<dim3(NH / 64, NB / 64, ZHA), 256, 0, stream>>>(
        A2c + 6144, KGC, nullptr, 0, Wha2t, KHA, HAP, NB, NH, KHA, KSH);
    // fused attention: logits + softmax + feat_hat -> A2c, out_att
    if (useF16)
      att_fused_k<true><<<NB, 256, 0, stream>>>(
          VA16, HAP, b_ha, W_a, b_a, FEAT16, nullptr, A2c, out_att, t);
    else
      att_fused_k<false><<<NB, 256, 0, stream>>>(
          VA16, HAP, b_ha, W_a, b_a, nullptr, feat, A2c, out_att, t);
    // gates_c partials = [feat_hat|h_v|h_c] @ Wgc  (8-way split-K)
    gemm_sk<false><<<dim3(H4 / 64, NB / 64, ZGC), 256, 0, stream>>>(
        A2c, KGC, nullptr, 0, Wgc2t, KGC, GP, NB, H4, KGC, KSC);
    lstm_pw_c_k<<<(NB * NH + 255) / 256, 256, 0, stream>>>(GP, b_c, CC, A2v, A2c, OUTH2, t);
  }

  // ---- classifier: out = OUTH2 @ W_cls + b_cls (m-inner grid, padded B rows) ----
  {
    dim3 g((NB * NT) / 128, VOCP / 128);
    gemm_mfma<false, false><<<g, 256, 0, stream>>>(
        OUTH2, KCL, Wcls2t, KCL, out_repr, VOC, b_cls, NB * NT, VOC, KCL);
  }
}

// Round 6
// 5128.485 us; speedup vs baseline: 3.7537x; 1.1726x over previous
//
#include <hip/hip_runtime.h>
#include <math.h>

namespace {

constexpr int NB  = 256;
constexpr int NT  = 20;
constexpr int NR  = 100;
constexpr int IND = 300;
constexpr int NH  = 1024;
constexpr int VD  = 2048;
constexpr int H4  = 4096;
constexpr int VOC = 10000;
constexpr int VOCP2 = 10240;  // vocab padded to 256

// packed K' layout: per original k, 3 slots. A side: [hi, lo, hi]; B side: [hi, hi, lo]
constexpr int KGV = 7072;
constexpr int KGC = 12288;
constexpr int KHA = 3072;
constexpr int KCL = 3072;
constexpr int A2VLD = 6144;   // A2v row: [h_c(3072) | h_v(3072)]; x-seg from X2
constexpr int X2LD  = 928;    // 900 packed + 28 zero pad (29 groups of 32)

constexpr int ZGV = 8; constexpr int KSV = 896;
constexpr int ZGC = 8; constexpr int KSC = 1536;
constexpr int ZHA = 8; constexpr int KSH = 384;

typedef short  s8v  __attribute__((ext_vector_type(8)));
typedef float  f4v  __attribute__((ext_vector_type(4)));

__device__ __forceinline__ float sigm(float x) { return 1.f / (1.f + expf(-x)); }
__device__ __forceinline__ unsigned short f2b(float x) {
  return __builtin_bit_cast(unsigned short, (__bf16)x);
}
__device__ __forceinline__ float b2f(unsigned short u) {
  return (float)__builtin_bit_cast(__bf16, u);
}
// swizzle: XOR the 8-elem slot index (bits 3-4 of k) with F(row)
__device__ __forceinline__ int Frow(int row) { return (row ^ (row >> 2)) & 3; }
// store split-bf16 triple (hi,lo,hi) at logical kq within a swizzled row
__device__ __forceinline__ void store3(unsigned short* rowbase, int kq, float x, int Fs) {
  const unsigned short h = f2b(x);
  const unsigned short l = f2b(x - b2f(h));
  rowbase[kq ^ Fs] = h;
  rowbase[(kq + 1) ^ Fs] = l;
  rowbase[(kq + 2) ^ Fs] = h;
}

__device__ __forceinline__ void gload16(const unsigned short* g, unsigned short* l) {
  __builtin_amdgcn_global_load_lds(
      (const __attribute__((address_space(1))) void*)g,
      (__attribute__((address_space(3))) void*)l, 16, 0, 0);
}

// =================== 256x256 bf16 MFMA GEMM, 8 waves, dbuf, swizzled ===========
// A [*,lda] bf16 swizzled rows; Bt [*,ldb] bf16 swizzled rows (>= grid.y*256 rows).
// grid: x = m-tiles (inner), y = n-tiles. Kp mult of 32. Epilogue guards gn<N.
template<bool OUT_BF16>
__global__ __launch_bounds__(512)
void gemm256(const unsigned short* __restrict__ A, int lda,
             const unsigned short* __restrict__ Bt, int ldb,
             void* __restrict__ Cv, int ldc,
             const float* __restrict__ bias,
             int N, int Kp)
{
  __shared__ unsigned short As[2][256 * 32];
  __shared__ unsigned short Bs[2][256 * 32];
  const int tid = threadIdx.x, wid = tid >> 6, lane = tid & 63;
  const int wm = (wid >> 2) * 128, wn = (wid & 3) * 64;
  const int m0 = blockIdx.x * 256, n0 = blockIdx.y * 256;
  const int sr = tid >> 2, sc = (tid & 3) * 8;
  const unsigned short* a0 = A + (size_t)(m0 + sr) * lda + sc;
  const unsigned short* a1 = A + (size_t)(m0 + 128 + sr) * lda + sc;
  const unsigned short* b0 = Bt + (size_t)(n0 + sr) * ldb + sc;
  const unsigned short* b1 = Bt + (size_t)(n0 + 128 + sr) * ldb + sc;

  const int rr = lane & 15;
  const int kc = (((lane >> 4) ^ Frow(rr)) & 3) * 8;

  f4v acc[8][4] = {};

  // prologue stage
  gload16(a0, &As[0][tid * 8]);
  gload16(a1, &As[0][4096 + tid * 8]);
  gload16(b0, &Bs[0][tid * 8]);
  gload16(b1, &Bs[0][4096 + tid * 8]);
  __syncthreads();

  int cur = 0;
  for (int k0 = 0; k0 < Kp; k0 += 32) {
    const int nxt = cur ^ 1;
    if (k0 + 32 < Kp) {   // issue next-tile loads BEFORE compute (2-phase overlap)
      gload16(a0 + k0 + 32, &As[nxt][tid * 8]);
      gload16(a1 + k0 + 32, &As[nxt][4096 + tid * 8]);
      gload16(b0 + k0 + 32, &Bs[nxt][tid * 8]);
      gload16(b1 + k0 + 32, &Bs[nxt][4096 + tid * 8]);
    }
    s8v a[8], b[4];
#pragma unroll
    for (int i = 0; i < 8; ++i) a[i] = *(const s8v*)&As[cur][(wm + i * 16 + rr) * 32 + kc];
#pragma unroll
    for (int j = 0; j < 4; ++j) b[j] = *(const s8v*)&Bs[cur][(wn + j * 16 + rr) * 32 + kc];
#pragma unroll
    for (int i = 0; i < 8; ++i)
#pragma unroll
      for (int j = 0; j < 4; ++j)
        acc[i][j] = __builtin_amdgcn_mfma_f32_16x16x32_bf16(a[i], b[j], acc[i][j], 0, 0, 0);
    __syncthreads();
    cur = nxt;
  }

  const int cr = (lane >> 4) * 4, cc = lane & 15;
#pragma unroll
  for (int i = 0; i < 8; ++i) {
#pragma unroll
    for (int j = 0; j < 4; ++j) {
      const int gn = n0 + wn + j * 16 + cc;
      if (gn >= N) continue;
#pragma unroll
      for (int r = 0; r < 4; ++r) {
        const int gm = m0 + wm + i * 16 + cr + r;
        float v = acc[i][j][r] + bias[gn];
        if constexpr (OUT_BF16) ((unsigned short*)Cv)[(size_t)gm * ldc + gn] = f2b(v);
        else                    ((float*)Cv)[(size_t)gm * ldc + gn] = v;
      }
    }
  }
}

// =================== split-K GEMM, M=256 full batch, BN=128, dbuf, swizzled =====
// Weights (Bt) staged exactly once; A (activations, small) re-staged from L2.
template<bool XSEG>
__global__ __launch_bounds__(512)
void gemm_sk2(const unsigned short* __restrict__ A, int lda,
              const unsigned short* __restrict__ X2, int t,
              const unsigned short* __restrict__ Bt, int ldb,
              float* __restrict__ P, int N, int Kp, int Ksplit)
{
  __shared__ unsigned short As[2][256 * 32];
  __shared__ unsigned short Bs[2][128 * 32];
  const int tid = threadIdx.x, wid = tid >> 6, lane = tid & 63;
  const int wm = (wid >> 2) * 128, wn = (wid & 3) * 32;
  const int n0 = blockIdx.x * 128;
  const int kbeg = blockIdx.z * Ksplit;
  const int kend = min(Kp, kbeg + Ksplit);
  const int sr = tid >> 2, sc = (tid & 3) * 8;
  const unsigned short* a0 = A + (size_t)sr * lda + sc;
  const unsigned short* a1 = A + (size_t)(128 + sr) * lda + sc;
  const unsigned short* x0 = nullptr;
  const unsigned short* x1 = nullptr;
  if constexpr (XSEG) {
    x0 = X2 + ((size_t)sr * NT + t) * X2LD + sc;
    x1 = X2 + ((size_t)(128 + sr) * NT + t) * X2LD + sc;
  }
  const unsigned short* b0 = Bt + (size_t)(n0 + sr) * ldb + sc;

  const int rr = lane & 15;
  const int kc = (((lane >> 4) ^ Frow(rr)) & 3) * 8;

  f4v acc[8][2] = {};

  auto stage = [&](int buf, int k) {
    if constexpr (XSEG) {
      if (k >= A2VLD) {
        gload16(x0 + (k - A2VLD), &As[buf][tid * 8]);
        gload16(x1 + (k - A2VLD), &As[buf][4096 + tid * 8]);
      } else {
        gload16(a0 + k, &As[buf][tid * 8]);
        gload16(a1 + k, &As[buf][4096 + tid * 8]);
      }
    } else {
      gload16(a0 + k, &As[buf][tid * 8]);
      gload16(a1 + k, &As[buf][4096 + tid * 8]);
    }
    gload16(b0 + k, &Bs[buf][tid * 8]);
  };

  stage(0, kbeg);
  __syncthreads();

  int cur = 0;
  for (int k0 = kbeg; k0 < kend; k0 += 32) {
    const int nxt = cur ^ 1;
    if (k0 + 32 < kend) stage(nxt, k0 + 32);
    s8v a[8], b[2];
#pragma unroll
    for (int i = 0; i < 8; ++i) a[i] = *(const s8v*)&As[cur][(wm + i * 16 + rr) * 32 + kc];
#pragma unroll
    for (int j = 0; j < 2; ++j) b[j] = *(const s8v*)&Bs[cur][(wn + j * 16 + rr) * 32 + kc];
#pragma unroll
    for (int i = 0; i < 8; ++i)
#pragma unroll
      for (int j = 0; j < 2; ++j)
        acc[i][j] = __builtin_amdgcn_mfma_f32_16x16x32_bf16(a[i], b[j], acc[i][j], 0, 0, 0);
    __syncthreads();
    cur = nxt;
  }

  float* out = P + (size_t)blockIdx.z * 256 * N;
  const int cr = (lane >> 4) * 4, cc = lane & 15;
#pragma unroll
  for (int i = 0; i < 8; ++i)
#pragma unroll
    for (int j = 0; j < 2; ++j)
#pragma unroll
      for (int r = 0; r < 4; ++r)
        out[(size_t)(wm + i * 16 + cr + r) * N + n0 + wn + j * 16 + cc] = acc[i][j][r];
}

// =================== 128x128 VA fallback (fp32 A converted on stage) ============
__global__ __launch_bounds__(256)
void gemm_va_f32(const float* __restrict__ A, int lda,
                 const unsigned short* __restrict__ Bt, int ldb,
                 unsigned short* __restrict__ C, int ldc,
                 const float* __restrict__ bias, int N, int Kp)
{
  __shared__ unsigned short As[128 * 32];
  __shared__ unsigned short Bs[128 * 32];
  const int tid = threadIdx.x, wid = tid >> 6, lane = tid & 63;
  const int wm = (wid >> 1) * 64, wn = (wid & 1) * 64;
  const int m0 = blockIdx.x * 128, n0 = blockIdx.y * 128;
  const unsigned short* bsrc0 = Bt + (size_t)(n0 + (tid >> 2)) * ldb + (tid & 3) * 8;
  const unsigned short* bsrc1 = bsrc0 + (size_t)64 * ldb;
  const int rr = lane & 15;
  const int kc = (((lane >> 4) ^ Frow(rr)) & 3) * 8;

  f4v acc[4][4] = {};
  for (int k0 = 0; k0 < Kp; k0 += 32) {
#pragma unroll
    for (int it = 0; it < 4; ++it) {
      const int r = it * 32 + (tid >> 3), c = (tid & 7) * 4;
      const float4 v = *(const float4*)(A + (size_t)(m0 + r) * lda + k0 + c);
      ushort4 w;
      w.x = f2b(v.x); w.y = f2b(v.y); w.z = f2b(v.z); w.w = f2b(v.w);
      *(ushort4*)&As[r * 32 + (c ^ (Frow(r & 15) << 3))] = w;   // store swizzled
    }
    gload16(bsrc0 + k0, &Bs[tid * 8]);
    gload16(bsrc1 + k0, &Bs[2048 + tid * 8]);
    __syncthreads();
    s8v a[4], b[4];
#pragma unroll
    for (int i = 0; i < 4; ++i) a[i] = *(const s8v*)&As[(wm + i * 16 + rr) * 32 + kc];
#pragma unroll
    for (int j = 0; j < 4; ++j) b[j] = *(const s8v*)&Bs[(wn + j * 16 + rr) * 32 + kc];
#pragma unroll
    for (int i = 0; i < 4; ++i)
#pragma unroll
      for (int j = 0; j < 4; ++j)
        acc[i][j] = __builtin_amdgcn_mfma_f32_16x16x32_bf16(a[i], b[j], acc[i][j], 0, 0, 0);
    __syncthreads();
  }
  const int cr = (lane >> 4) * 4, cc = lane & 15;
#pragma unroll
  for (int i = 0; i < 4; ++i)
#pragma unroll
    for (int j = 0; j < 4; ++j) {
      const int gn = n0 + wn + j * 16 + cc;
      if (gn >= N) continue;
#pragma unroll
      for (int r = 0; r < 4; ++r)
        C[(size_t)(m0 + wm + i * 16 + cr + r) * ldc + gn] = f2b(acc[i][j][r] + bias[gn]);
    }
}

// =================== fp32 GEMM (setup-only) ===================
__global__ __launch_bounds__(256)
void gemm_f32(const float* __restrict__ Ap, int lda,
              const float* __restrict__ Bp, int ldb,
              float* __restrict__ Cp, int ldc,
              const float* __restrict__ bias,
              int M, int N, int K)
{
  __shared__ float As[16][64];
  __shared__ float Bs[16][64];
  const int n0 = blockIdx.x * 64, m0 = blockIdx.y * 64;
  const int tid = threadIdx.x;
  const int tx = tid & 15, ty = tid >> 4;
  float acc[4][4] = {};
  for (int k0 = 0; k0 < K; k0 += 16) {
    {
      const int e = tid << 2;
      const int m = e >> 4, k = e & 15;
      const int gm = m0 + m, gk = k0 + k;
      float4 v = make_float4(0.f, 0.f, 0.f, 0.f);
      if (gm < M) {
        const float* src = Ap + (size_t)gm * lda + gk;
        if (gk + 3 < K) v = *(const float4*)src;
        else {
          if (gk     < K) v.x = src[0];
          if (gk + 1 < K) v.y = src[1];
          if (gk + 2 < K) v.z = src[2];
          if (gk + 3 < K) v.w = src[3];
        }
      }
      As[k][m] = v.x; As[k + 1][m] = v.y; As[k + 2][m] = v.z; As[k + 3][m] = v.w;
    }
    {
      const int e = tid << 2;
      const int k = e >> 6, n = e & 63;
      const int gk = k0 + k, gn = n0 + n;
      float4 v = make_float4(0.f, 0.f, 0.f, 0.f);
      if (gk < K) {
        const float* src = Bp + (size_t)gk * ldb + gn;
        if (gn + 3 < N) v = *(const float4*)src;
        else {
          if (gn     < N) v.x = src[0];
          if (gn + 1 < N) v.y = src[1];
          if (gn + 2 < N) v.z = src[2];
          if (gn + 3 < N) v.w = src[3];
        }
      }
      Bs[k][n] = v.x; Bs[k][n + 1] = v.y; Bs[k][n + 2] = v.z; Bs[k][n + 3] = v.w;
    }
    __syncthreads();
#pragma unroll
    for (int k = 0; k < 16; ++k) {
      const float a0 = As[k][ty * 4 + 0], a1 = As[k][ty * 4 + 1];
      const float a2 = As[k][ty * 4 + 2], a3 = As[k][ty * 4 + 3];
      const float b0 = Bs[k][tx * 4 + 0], b1 = Bs[k][tx * 4 + 1];
      const float b2 = Bs[k][tx * 4 + 2], b3 = Bs[k][tx * 4 + 3];
      acc[0][0] += a0 * b0; acc[0][1] += a0 * b1; acc[0][2] += a0 * b2; acc[0][3] += a0 * b3;
      acc[1][0] += a1 * b0; acc[1][1] += a1 * b1; acc[1][2] += a1 * b2; acc[1][3] += a1 * b3;
      acc[2][0] += a2 * b0; acc[2][1] += a2 * b1; acc[2][2] += a2 * b2; acc[2][3] += a2 * b3;
      acc[3][0] += a3 * b0; acc[3][1] += a3 * b1; acc[3][2] += a3 * b2; acc[3][3] += a3 * b3;
    }
    __syncthreads();
  }
#pragma unroll
  for (int i = 0; i < 4; ++i) {
    const int gm = m0 + ty * 4 + i;
    if (gm >= M) continue;
#pragma unroll
    for (int j = 0; j < 4; ++j) {
      const int gn = n0 + tx * 4 + j;
      if (gn >= N) continue;
      Cp[(size_t)gm * ldc + gn] = acc[i][j] + bias[gn];
    }
  }
}

// =================== weight transpose+convert (swizzled dst) ===================
__global__ void convB_k(const float* __restrict__ src, int srcld, int K, int N,
                        unsigned short* __restrict__ dst, int dstld, int coff, int mode)
{
  __shared__ float t[32][33];
  const int kb = blockIdx.x * 32, nb = blockIdx.y * 32;
  const int tx = threadIdx.x & 31, ty = threadIdx.x >> 5;
#pragma unroll
  for (int i = 0; i < 32; i += 8) {
    const int k = kb + ty + i, n = nb + tx;
    t[ty + i][tx] = (k < K && n < N) ? src[(size_t)k * srcld + n] : 0.f;
  }
  __syncthreads();
#pragma unroll
  for (int i = 0; i < 32; i += 8) {
    const int n = nb + ty + i, k = kb + tx;
    if (n >= N || k >= K) continue;
    const float x = t[tx][ty + i];
    const int Fs = Frow(n & 15) << 3;
    unsigned short* row = dst + (size_t)n * dstld;
    if (mode == 0) {
      const unsigned short h = f2b(x);
      const unsigned short l = f2b(x - b2f(h));
      const int kq = coff + 3 * k;
      row[kq ^ Fs] = h;
      row[(kq + 1) ^ Fs] = h;
      row[(kq + 2) ^ Fs] = l;
    } else {
      row[(coff + k) ^ Fs] = f2b(x);
    }
  }
}

// zero LOGICAL columns [c0, ld) for rows [0, N), swizzled
__global__ void zpad_k(unsigned short* __restrict__ dst, int ld, int c0, int N)
{
  const int w = ld - c0;
  const int idx = blockIdx.x * 256 + threadIdx.x;
  if (idx >= N * w) return;
  const int n = idx / w, c = c0 + (idx % w);
  dst[(size_t)n * ld + (c ^ (Frow(n & 15) << 3))] = 0;
}

__global__ void zfill_k(unsigned short* __restrict__ p, int n)
{
  const int i = blockIdx.x * 256 + threadIdx.x;
  if (i < n) p[i] = 0;
}

// =================== small kernels ===================
__global__ void feat_mean_k(const float* __restrict__ feat, float* __restrict__ fm)
{
  const int idx = blockIdx.x * 256 + threadIdx.x;
  if (idx >= NB * VD) return;
  const int d = idx % VD, b = idx / VD;
  const float* base = feat + (size_t)b * NR * VD + d;
  float s = 0.f;
  for (int r = 0; r < NR; ++r) s += base[(size_t)r * VD];
  fm[idx] = s * (1.f / NR);
}

// features f32 -> bf16 swizzled
__global__ void f2b8_k(const float* __restrict__ in, unsigned short* __restrict__ out, long n8)
{
  for (long i = blockIdx.x * 256 + threadIdx.x; i < n8; i += (long)gridDim.x * 256) {
    const float4 a = *(const float4*)(in + i * 8);
    const float4 b = *(const float4*)(in + i * 8 + 4);
    unsigned short w[8] = {f2b(a.x), f2b(a.y), f2b(a.z), f2b(a.w),
                           f2b(b.x), f2b(b.y), f2b(b.z), f2b(b.w)};
    const long row = i >> 8;                 // VD/8 = 256 chunks per row
    const int  c   = (int)(i & 255) * 8;
    *(s8v*)(out + row * VD + (c ^ (Frow((int)row & 15) << 3))) = *(const s8v*)w;
  }
}

// X2 builder: logical c in [0,X2LD), swizzled by F(b)
__global__ void build_x2_k(const int* __restrict__ cap, const float* __restrict__ emb,
                           const float* __restrict__ vinp, unsigned short* __restrict__ X2)
{
  const int idx = blockIdx.x * 256 + threadIdx.x;
  if (idx >= NB * NT * X2LD) return;
  const int c = idx % X2LD;
  const int bt = idx / X2LD;
  const int t = bt % NT, b = bt / NT;
  const int Fs = Frow(b & 15) << 3;
  unsigned short val = 0;
  if (c < 900) {
    const int d = c / 3, s = c % 3;
    const float v = (t == 0) ? vinp[b * IND + d]
                             : emb[(size_t)cap[b * (NT - 1) + (t - 1)] * IND + d];
    const unsigned short h = f2b(v);
    val = (s == 1) ? f2b(v - b2f(h)) : h;
  }
  X2[(size_t)bt * X2LD + (c ^ Fs)] = val;
}

__global__ void lstm_pw_v_k(const float* __restrict__ gp, const float* __restrict__ fmg,
                            float* __restrict__ cv,
                            unsigned short* __restrict__ A2c, unsigned short* __restrict__ A2v)
{
  const int idx = blockIdx.x * 256 + threadIdx.x;
  if (idx >= NB * NH) return;
  const int n = idx & (NH - 1), b = idx >> 10;
  const size_t base = (size_t)b * H4;
  float gi = fmg[base + n], gf = fmg[base + NH + n];
  float gg = fmg[base + 2 * NH + n], go = fmg[base + 3 * NH + n];
#pragma unroll
  for (int z = 0; z < ZGV; ++z) {
    const float* g = gp + (size_t)z * NB * H4 + base;
    gi += g[n]; gf += g[NH + n]; gg += g[2 * NH + n]; go += g[3 * NH + n];
  }
  const float c2 = sigm(gf) * cv[idx] + sigm(gi) * tanhf(gg);
  const float h2 = sigm(go) * tanhf(c2);
  cv[idx] = c2;
  const int Fs = Frow(b & 15) << 3;
  store3(A2c + (size_t)b * KGC, 6144 + 3 * n, h2, Fs);
  store3(A2v + (size_t)b * A2VLD, 3072 + 3 * n, h2, Fs);
}

__global__ void lstm_pw_c_k(const float* __restrict__ gp, const float* __restrict__ bc,
                            float* __restrict__ cc,
                            unsigned short* __restrict__ A2v, unsigned short* __restrict__ A2c,
                            unsigned short* __restrict__ outh2, int t)
{
  const int idx = blockIdx.x * 256 + threadIdx.x;
  if (idx >= NB * NH) return;
  const int n = idx & (NH - 1), b = idx >> 10;
  const size_t base = (size_t)b * H4;
  float gi = bc[n], gf = bc[NH + n], gg = bc[2 * NH + n], go = bc[3 * NH + n];
#pragma unroll
  for (int z = 0; z < ZGC; ++z) {
    const float* g = gp + (size_t)z * NB * H4 + base;
    gi += g[n]; gf += g[NH + n]; gg += g[2 * NH + n]; go += g[3 * NH + n];
  }
  const float c2 = sigm(gf) * cc[idx] + sigm(gi) * tanhf(gg);
  const float h2 = sigm(go) * tanhf(c2);
  cc[idx] = c2;
  const int Fs = Frow(b & 15) << 3;
  store3(A2v + (size_t)b * A2VLD, 3 * n, h2, Fs);
  store3(A2c + (size_t)b * KGC, 9216 + 3 * n, h2, Fs);
  const int ro = b * NT + t;
  store3(outh2 + (size_t)ro * KCL, 3 * n, h2, Frow(ro & 15) << 3);
}

// HA = b_ha + sum_z HAP[z]
__global__ void ha_red_k(const float* __restrict__ hap, const float* __restrict__ bha,
                         float* __restrict__ ha)
{
  const int idx = blockIdx.x * 256 + threadIdx.x;
  if (idx >= NB * NH) return;
  float s = bha[idx & (NH - 1)];
#pragma unroll
  for (int z = 0; z < ZHA; ++z) s += hap[(size_t)z * NB * NH + idx];
  ha[idx] = s;
}

// attention logits: grid (4 rgroups, NB); 25 regions per block
__global__ __launch_bounds__(256)
void att_logits_k(const unsigned short* __restrict__ va16,
                  const float* __restrict__ ha,
                  const float* __restrict__ Wa, const float* __restrict__ ba,
                  float* __restrict__ logits)
{
  const int rg = blockIdx.x, b = blockIdx.y;
  const int tid = threadIdx.x, lane = tid & 63, wid = tid >> 6;
  __shared__ float ha_s[NH];
  __shared__ float wa_s[NH];
  for (int j = tid; j < NH; j += 256) {
    ha_s[j] = ha[(size_t)b * NH + j];
    wa_s[j] = Wa[j];
  }
  __syncthreads();
  for (int r0 = wid; r0 < 25; r0 += 4) {
    const int r = rg * 25 + r0;
    const unsigned short* vrow = va16 + ((size_t)b * NR + r) * NH + lane * 16;
    float s = 0.f;
#pragma unroll
    for (int u = 0; u < 2; ++u) {
      const s8v v = *(const s8v*)(vrow + u * 8);
      const int j0 = lane * 16 + u * 8;
#pragma unroll
      for (int e = 0; e < 8; ++e)
        s += tanhf(b2f((unsigned short)v[e]) + ha_s[j0 + e]) * wa_s[j0 + e];
    }
    for (int o = 32; o; o >>= 1) s += __shfl_down(s, o);
    if (lane == 0) logits[b * NR + r] = s + ba[0];
  }
}

// softmax + feat_hat + pack: grid NB, 256 thr
template<bool F16>
__global__ __launch_bounds__(256)
void att_fh_k(const float* __restrict__ logits,
              const unsigned short* __restrict__ f16,
              const float* __restrict__ f32,
              unsigned short* __restrict__ A2c,
              float* __restrict__ att_out, int t)
{
  const int b = blockIdx.x, tid = threadIdx.x;
  const int lane = tid & 63, wid = tid >> 6;
  __shared__ float red_s[128];
  if (tid < 128) red_s[tid] = (tid < NR) ? logits[b * NR + tid] : -3.4e38f;
  __syncthreads();
  if (wid == 0) {
    float v0 = red_s[lane];
    float v1 = red_s[lane + 64];
    float m = fmaxf(v0, v1);
    for (int o = 32; o; o >>= 1) m = fmaxf(m, __shfl_xor(m, o));
    const float e0 = (lane < NR) ? expf(v0 - m) : 0.f;
    const float e1 = (lane + 64 < NR) ? expf(v1 - m) : 0.f;
    float s = e0 + e1;
    for (int o = 32; o; o >>= 1) s += __shfl_xor(s, o);
    const float inv = 1.f / s;
    red_s[lane] = e0 * inv;
    red_s[lane + 64] = e1 * inv;
  }
  __syncthreads();
  if (tid < NR) att_out[((size_t)b * NT + t) * NR + tid] = red_s[tid];

  const int d0 = tid * 8;
  float fh[8] = {};
  if constexpr (F16) {
    const unsigned short* fbase = f16 + (size_t)b * NR * VD;
    for (int r = 0; r < NR; ++r) {
      const int ro = b * NR + r;
      const s8v f = *(const s8v*)(fbase + (size_t)r * VD + (d0 ^ (Frow(ro & 15) << 3)));
      const float a = red_s[r];
#pragma unroll
      for (int e = 0; e < 8; ++e) fh[e] += a * b2f((unsigned short)f[e]);
    }
  } else {
    const float* fb = f32 + (size_t)b * NR * VD + d0;
    for (int r = 0; r < NR; ++r) {
      const float4 x0 = *(const float4*)(fb + (size_t)r * VD);
      const float4 x1 = *(const float4*)(fb + (size_t)r * VD + 4);
      const float a = red_s[r];
      fh[0] += a * x0.x; fh[1] += a * x0.y; fh[2] += a * x0.z; fh[3] += a * x0.w;
      fh[4] += a * x1.x; fh[5] += a * x1.y; fh[6] += a * x1.z; fh[7] += a * x1.w;
    }
  }
  unsigned short* rowbase = A2c + (size_t)b * KGC;
  const int Fs = Frow(b & 15) << 3;
#pragma unroll
  for (int e = 0; e < 8; ++e) store3(rowbase, 3 * (d0 + e), fh[e] * (1.f / NR), Fs);
}

inline void gemmF(hipStream_t st, const float* A, int lda, const float* B, int ldb,
                  float* C, int ldc, const float* bias, int M, int N, int K)
{
  dim3 g((N + 63) / 64, (M + 63) / 64);
  gemm_f32<<<g, 256, 0, st>>>(A, lda, B, ldb, C, ldc, bias, M, N, K);
}

inline void convB(hipStream_t st, const float* src, int srcld, int K, int N,
                  unsigned short* dst, int dstld, int coff, int mode)
{
  dim3 g((K + 31) / 32, (N + 31) / 32);
  convB_k<<<g, 256, 0, st>>>(src, srcld, K, N, dst, dstld, coff, mode);
}

} // namespace

extern "C" void kernel_launch(void* const* d_in, const int* in_sizes, int n_in,
                              void* d_out, int out_size, void* d_ws, size_t ws_size,
                              hipStream_t stream)
{
  const int*   caption = (const int*)  d_in[0];
  const float* feat    = (const float*)d_in[1];
  const float* emb     = (const float*)d_in[2];
  const float* W_vin   = (const float*)d_in[3];
  const float* b_vin   = (const float*)d_in[4];
  const float* W_ih_v  = (const float*)d_in[5];
  const float* W_hh_v  = (const float*)d_in[6];
  const float* b_v     = (const float*)d_in[7];
  const float* W_va    = (const float*)d_in[8];
  const float* b_va    = (const float*)d_in[9];
  const float* W_ha    = (const float*)d_in[10];
  const float* b_ha    = (const float*)d_in[11];
  const float* W_a     = (const float*)d_in[12];
  const float* b_a     = (const float*)d_in[13];
  const float* W_ih_c  = (const float*)d_in[14];
  const float* W_hh_c  = (const float*)d_in[15];
  const float* b_c     = (const float*)d_in[16];
  const float* W_cls   = (const float*)d_in[17];
  const float* b_cls   = (const float*)d_in[18];

  float* out_repr = (float*)d_out;                       // [NB,NT,VOC]
  float* out_att  = out_repr + (size_t)NB * NT * VOC;    // [NB,NT,NR]

  char* cur = (char*)d_ws;
  auto take = [&](size_t bytes) { char* p = cur; cur += bytes; return p; };

  unsigned short* A2v  = (unsigned short*)take((size_t)NB * A2VLD * 2);
  unsigned short* A2c  = (unsigned short*)take((size_t)NB * KGC * 2);
  float* CV            = (float*)take((size_t)NB * NH * 4);
  float* CC            = (float*)take((size_t)NB * NH * 4);
  const size_t ZERO_BYTES = (size_t)NB * A2VLD * 2 + (size_t)NB * KGC * 2
                          + 2 * (size_t)NB * NH * 4;

  float* FM            = (float*)take((size_t)NB * VD * 4);
  float* VINP          = (float*)take((size_t)NB * IND * 4);
  unsigned short* X2   = (unsigned short*)take((size_t)NB * NT * X2LD * 2);
  float* FMG           = (float*)take((size_t)NB * H4 * 4);
  unsigned short* VA16 = (unsigned short*)take((size_t)NB * NR * NH * 2);   // 52MB
  float* GP            = (float*)take((size_t)ZGC * NB * H4 * 4);           // 33.5MB
  float* HAP           = (float*)take((size_t)ZHA * NB * NH * 4);           // 8.4MB
  float* HA            = (float*)take((size_t)NB * NH * 4);
  float* LOG           = (float*)take((size_t)NB * NR * 4);
  unsigned short* OUTH2= (unsigned short*)take((size_t)NB * NT * KCL * 2);  // 31.5MB
  unsigned short* Wgv2t= (unsigned short*)take((size_t)H4 * KGV * 2);       // 58MB
  unsigned short* Wha2t= (unsigned short*)take((size_t)NH * KHA * 2);
  unsigned short* Wgc2t= (unsigned short*)take((size_t)H4 * KGC * 2);       // 101MB
  unsigned short* Wcls2t=(unsigned short*)take((size_t)VOCP2 * KCL * 2);    // 63MB
  unsigned short* Wva16t=(unsigned short*)take((size_t)NH * VD * 2);
  unsigned short* FEAT16=(unsigned short*)cur;                              // 105MB optional
  const bool useF16 = ((size_t)(cur - (char*)d_ws) + (size_t)NB * NR * VD * 2) <= ws_size;

  hipMemsetAsync(A2v, 0, ZERO_BYTES, stream);

  // ---- weight conversions (swizzled) ----
  convB(stream, W_ih_v + (size_t)2048 * H4, H4, 1024, H4, Wgv2t, KGV, 0,    0);
  convB(stream, W_hh_v,                     H4, 1024, H4, Wgv2t, KGV, 3072, 0);
  convB(stream, W_ih_v + (size_t)3072 * H4, H4, 300,  H4, Wgv2t, KGV, 6144, 0);
  zpad_k<<<((H4 * (KGV - 7044)) + 255) / 256, 256, 0, stream>>>(Wgv2t, KGV, 7044, H4);
  convB(stream, W_ha, NH, 1024, NH, Wha2t, KHA, 0, 0);
  convB(stream, W_ih_c,                     H4, 2048, H4, Wgc2t, KGC, 0,    0);
  convB(stream, W_ih_c + (size_t)2048 * H4, H4, 1024, H4, Wgc2t, KGC, 6144, 0);
  convB(stream, W_hh_c,                     H4, 1024, H4, Wgc2t, KGC, 9216, 0);
  convB(stream, W_cls, VOC, 1024, VOC, Wcls2t, KCL, 0, 0);
  zfill_k<<<(((VOCP2 - VOC) * KCL) + 255) / 256, 256, 0, stream>>>(
      Wcls2t + (size_t)VOC * KCL, (VOCP2 - VOC) * KCL);
  convB(stream, W_va, NH, VD, NH, Wva16t, VD, 0, 1);

  // ---- setup ----
  feat_mean_k<<<(NB * VD + 255) / 256, 256, 0, stream>>>(feat, FM);
  gemmF(stream, FM, VD, W_vin, IND, VINP, IND, b_vin, NB, IND, VD);
  build_x2_k<<<(NB * NT * X2LD + 255) / 256, 256, 0, stream>>>(caption, emb, VINP, X2);
  gemmF(stream, FM, VD, W_ih_v, H4, FMG, H4, b_v, NB, H4, VD);
  if (useF16) {
    f2b8_k<<<2048, 256, 0, stream>>>(feat, FEAT16, (long)NB * NR * VD / 8);
    dim3 g((NB * NR) / 256, NH / 256);
    gemm256<true><<<g, 512, 0, stream>>>(FEAT16, VD, Wva16t, VD, VA16, NH, b_va, NH, VD);
  } else {
    dim3 g((NB * NR) / 128, NH / 128);
    gemm_va_f32<<<g, 256, 0, stream>>>(feat, VD, Wva16t, VD, VA16, NH, b_va, NH, VD);
  }

  // ---- sequential decode ----
  for (int t = 0; t < NT; ++t) {
    gemm_sk2<true><<<dim3(H4 / 128, 1, ZGV), 512, 0, stream>>>(
        A2v, A2VLD, X2, t, Wgv2t, KGV, GP, H4, KGV, KSV);
    lstm_pw_v_k<<<(NB * NH + 255) / 256, 256, 0, stream>>>(GP, FMG, CV, A2c, A2v);
    gemm_sk2<false><<<dim3(NH / 128, 1, ZHA), 512, 0, stream>>>(
        A2c + 6144, KGC, nullptr, 0, Wha2t, KHA, HAP, NH, KHA, KSH);
    ha_red_k<<<(NB * NH + 255) / 256, 256, 0, stream>>>(HAP, b_ha, HA);
    att_logits_k<<<dim3(4, NB), 256, 0, stream>>>(VA16, HA, W_a, b_a, LOG);
    if (useF16)
      att_fh_k<true><<<NB, 256, 0, stream>>>(LOG, FEAT16, nullptr, A2c, out_att, t);
    else
      att_fh_k<false><<<NB, 256, 0, stream>>>(LOG, nullptr, feat, A2c, out_att, t);
    gemm_sk2<false><<<dim3(H4 / 128, 1, ZGC), 512, 0, stream>>>(
        A2c, KGC, nullptr, 0, Wgc2t, KGC, GP, H4, KGC, KSC);
    lstm_pw_c_k<<<(NB * NH + 255) / 256, 256, 0, stream>>>(GP, b_c, CC, A2v, A2c, OUTH2, t);
  }

  // ---- classifier: 256x256 tiles, m-inner ----
  {
    dim3 g((NB * NT) / 256, VOCP2 / 256);
    gemm256<false><<<g, 512, 0, stream>>>(
        OUTH2, KCL, Wcls2t, KCL, out_repr, VOC, b_cls, VOC, KCL);
  }
}

// Round 7
// 4799.990 us; speedup vs baseline: 4.0106x; 1.0684x over previous
//
#include <hip/hip_runtime.h>
#include <math.h>

namespace {

constexpr int NB  = 256;
constexpr int NT  = 20;
constexpr int NR  = 100;
constexpr int IND = 300;
constexpr int NH  = 1024;
constexpr int VD  = 2048;
constexpr int H4  = 4096;
constexpr int VOC = 10000;
constexpr int VOCP2 = 10240;  // vocab padded to 256

// packed K' layout: per original k, 3 slots. A side: [hi, lo, hi]; B side: [hi, hi, lo]
constexpr int KGV = 7072;
constexpr int KGC = 12288;
constexpr int KHA = 3072;
constexpr int KCL = 3072;
constexpr int A2VLD = 6144;   // A2v row: [h_c(3072) | h_v(3072)]; x-seg from X2
constexpr int X2LD  = 928;    // 900 packed + 28 zero pad

constexpr int ZGV = 8; constexpr int KSV = 896;
constexpr int ZGC = 8; constexpr int KSC = 1536;
constexpr int ZHA = 8; constexpr int KSH = 384;

typedef short  s8v  __attribute__((ext_vector_type(8)));
typedef float  f4v  __attribute__((ext_vector_type(4)));

__device__ __forceinline__ float sigm(float x) { return 1.f / (1.f + expf(-x)); }
__device__ __forceinline__ unsigned short f2b(float x) {
  return __builtin_bit_cast(unsigned short, (__bf16)x);
}
__device__ __forceinline__ float b2f(unsigned short u) {
  return (float)__builtin_bit_cast(__bf16, u);
}
// swizzle: XOR the 8-elem slot index (bits 3-4 of k) with F(row)
__device__ __forceinline__ int Frow(int row) { return (row ^ (row >> 2)) & 3; }
__device__ __forceinline__ void store3(unsigned short* rowbase, int kq, float x, int Fs) {
  const unsigned short h = f2b(x);
  const unsigned short l = f2b(x - b2f(h));
  rowbase[kq ^ Fs] = h;
  rowbase[(kq + 1) ^ Fs] = l;
  rowbase[(kq + 2) ^ Fs] = h;
}

__device__ __forceinline__ void gload16(const unsigned short* g, unsigned short* l) {
  __builtin_amdgcn_global_load_lds(
      (const __attribute__((address_space(1))) void*)g,
      (__attribute__((address_space(3))) void*)l, 16, 0, 0);
}

// pipeline fences
#define BARRIER()  do { __builtin_amdgcn_s_barrier(); asm volatile("" ::: "memory"); } while (0)
#define VMWAIT(N)  asm volatile("s_waitcnt vmcnt(" #N ")" ::: "memory")

// =================== 256x256 bf16 MFMA GEMM, depth-3 counted pipeline ===========
// A [*,lda] bf16 swizzled rows; Bt [*,ldb] swizzled rows (>= grid.y*256 rows).
// grid: x = m-tiles, y = n-tiles. Kp mult of 32, Kp >= 96. Epilogue guards gn<N.
template<bool OUT_BF16>
__global__ __launch_bounds__(512)
void gemm256(const unsigned short* __restrict__ A, int lda,
             const unsigned short* __restrict__ Bt, int ldb,
             void* __restrict__ Cv, int ldc,
             const float* __restrict__ bias,
             int N, int Kp)
{
  __shared__ unsigned short As[3][256 * 32];
  __shared__ unsigned short Bs[3][256 * 32];
  const int tid = threadIdx.x, wid = tid >> 6, lane = tid & 63;
  const int wm = (wid >> 2) * 128, wn = (wid & 3) * 64;
  const int m0 = blockIdx.x * 256, n0 = blockIdx.y * 256;
  const int sr = tid >> 2, sc = (tid & 3) * 8;
  const unsigned short* a0 = A + (size_t)(m0 + sr) * lda + sc;
  const unsigned short* a1 = A + (size_t)(m0 + 128 + sr) * lda + sc;
  const unsigned short* b0 = Bt + (size_t)(n0 + sr) * ldb + sc;
  const unsigned short* b1 = Bt + (size_t)(n0 + 128 + sr) * ldb + sc;
  const int rr = lane & 15;
  const int kc = (((lane >> 4) ^ Frow(rr)) & 3) * 8;

  f4v acc[8][4] = {};

  auto stage = [&](int s, int k) {
    gload16(a0 + k, &As[s][tid * 8]);
    gload16(a1 + k, &As[s][4096 + tid * 8]);
    gload16(b0 + k, &Bs[s][tid * 8]);
    gload16(b1 + k, &Bs[s][4096 + tid * 8]);
  };
  auto compute = [&](int s) {
    s8v a[8], b[4];
#pragma unroll
    for (int i = 0; i < 8; ++i) a[i] = *(const s8v*)&As[s][(wm + i * 16 + rr) * 32 + kc];
#pragma unroll
    for (int j = 0; j < 4; ++j) b[j] = *(const s8v*)&Bs[s][(wn + j * 16 + rr) * 32 + kc];
#pragma unroll
    for (int i = 0; i < 8; ++i)
#pragma unroll
      for (int j = 0; j < 4; ++j)
        acc[i][j] = __builtin_amdgcn_mfma_f32_16x16x32_bf16(a[i], b[j], acc[i][j], 0, 0, 0);
  };

  // prologue: 3 buffers in flight; wait only for the oldest (counted, never 0)
  stage(0, 0); stage(1, 32); stage(2, 64);
  VMWAIT(8);
  BARRIER();

  int s = 0;
  int k0 = 0;
  for (; k0 + 96 < Kp; k0 += 32) {
    compute(s);
    BARRIER();                 // all waves done reading buf s
    stage(s, k0 + 96);         // overwrite s, 3 steps ahead
    VMWAIT(8);                 // oldest in-flight buffer (next to compute) landed
    BARRIER();
    s = (s == 2) ? 0 : s + 1;
  }
  // tail: buffers s, s+1, s+2 hold k0, k0+32, k0+64 (k0+96 == Kp)
  compute(s);
  VMWAIT(4);
  BARRIER();
  s = (s == 2) ? 0 : s + 1;
  compute(s);
  VMWAIT(0);
  BARRIER();
  s = (s == 2) ? 0 : s + 1;
  compute(s);

  const int cr = (lane >> 4) * 4, cc = lane & 15;
#pragma unroll
  for (int i = 0; i < 8; ++i) {
#pragma unroll
    for (int j = 0; j < 4; ++j) {
      const int gn = n0 + wn + j * 16 + cc;
      if (gn >= N) continue;
#pragma unroll
      for (int r = 0; r < 4; ++r) {
        const int gm = m0 + wm + i * 16 + cr + r;
        float v = acc[i][j][r] + bias[gn];
        if constexpr (OUT_BF16) ((unsigned short*)Cv)[(size_t)gm * ldc + gn] = f2b(v);
        else                    ((float*)Cv)[(size_t)gm * ldc + gn] = v;
      }
    }
  }
}

// =================== split-K GEMM, M=256, BN=128, depth-3 counted pipeline ======
// Ksplit range must be >= 96 (all call sites satisfy).
template<bool XSEG>
__global__ __launch_bounds__(512)
void gemm_sk2(const unsigned short* __restrict__ A, int lda,
              const unsigned short* __restrict__ X2, int t,
              const unsigned short* __restrict__ Bt, int ldb,
              float* __restrict__ P, int N, int Kp, int Ksplit)
{
  __shared__ unsigned short As[3][256 * 32];
  __shared__ unsigned short Bs[3][128 * 32];
  const int tid = threadIdx.x, wid = tid >> 6, lane = tid & 63;
  const int wm = (wid >> 2) * 128, wn = (wid & 3) * 32;
  const int n0 = blockIdx.x * 128;
  const int kbeg = blockIdx.z * Ksplit;
  const int kend = min(Kp, kbeg + Ksplit);
  const int sr = tid >> 2, sc = (tid & 3) * 8;
  const unsigned short* a0 = A + (size_t)sr * lda + sc;
  const unsigned short* a1 = A + (size_t)(128 + sr) * lda + sc;
  const unsigned short* x0 = nullptr;
  const unsigned short* x1 = nullptr;
  if constexpr (XSEG) {
    x0 = X2 + ((size_t)sr * NT + t) * X2LD + sc;
    x1 = X2 + ((size_t)(128 + sr) * NT + t) * X2LD + sc;
  }
  const unsigned short* b0 = Bt + (size_t)(n0 + sr) * ldb + sc;
  const int rr = lane & 15;
  const int kc = (((lane >> 4) ^ Frow(rr)) & 3) * 8;

  f4v acc[8][2] = {};

  auto stage = [&](int buf, int k) {
    if constexpr (XSEG) {
      if (k >= A2VLD) {
        gload16(x0 + (k - A2VLD), &As[buf][tid * 8]);
        gload16(x1 + (k - A2VLD), &As[buf][4096 + tid * 8]);
      } else {
        gload16(a0 + k, &As[buf][tid * 8]);
        gload16(a1 + k, &As[buf][4096 + tid * 8]);
      }
    } else {
      gload16(a0 + k, &As[buf][tid * 8]);
      gload16(a1 + k, &As[buf][4096 + tid * 8]);
    }
    gload16(b0 + k, &Bs[buf][tid * 8]);
  };
  auto compute = [&](int s) {
    s8v a[8], b[2];
#pragma unroll
    for (int i = 0; i < 8; ++i) a[i] = *(const s8v*)&As[s][(wm + i * 16 + rr) * 32 + kc];
#pragma unroll
    for (int j = 0; j < 2; ++j) b[j] = *(const s8v*)&Bs[s][(wn + j * 16 + rr) * 32 + kc];
#pragma unroll
    for (int i = 0; i < 8; ++i)
#pragma unroll
      for (int j = 0; j < 2; ++j)
        acc[i][j] = __builtin_amdgcn_mfma_f32_16x16x32_bf16(a[i], b[j], acc[i][j], 0, 0, 0);
  };

  stage(0, kbeg); stage(1, kbeg + 32); stage(2, kbeg + 64);
  VMWAIT(6);
  BARRIER();

  int s = 0;
  int k0 = kbeg;
  for (; k0 + 96 < kend; k0 += 32) {
    compute(s);
    BARRIER();
    stage(s, k0 + 96);
    VMWAIT(6);
    BARRIER();
    s = (s == 2) ? 0 : s + 1;
  }
  compute(s);
  VMWAIT(3);
  BARRIER();
  s = (s == 2) ? 0 : s + 1;
  compute(s);
  VMWAIT(0);
  BARRIER();
  s = (s == 2) ? 0 : s + 1;
  compute(s);

  float* out = P + (size_t)blockIdx.z * 256 * N;
  const int cr = (lane >> 4) * 4, cc = lane & 15;
#pragma unroll
  for (int i = 0; i < 8; ++i)
#pragma unroll
    for (int j = 0; j < 2; ++j)
#pragma unroll
      for (int r = 0; r < 4; ++r)
        out[(size_t)(wm + i * 16 + cr + r) * N + n0 + wn + j * 16 + cc] = acc[i][j][r];
}

// =================== 128x128 VA fallback (fp32 A converted on stage) ============
__global__ __launch_bounds__(256)
void gemm_va_f32(const float* __restrict__ A, int lda,
                 const unsigned short* __restrict__ Bt, int ldb,
                 unsigned short* __restrict__ C, int ldc,
                 const float* __restrict__ bias, int N, int Kp)
{
  __shared__ unsigned short As[128 * 32];
  __shared__ unsigned short Bs[128 * 32];
  const int tid = threadIdx.x, wid = tid >> 6, lane = tid & 63;
  const int wm = (wid >> 1) * 64, wn = (wid & 1) * 64;
  const int m0 = blockIdx.x * 128, n0 = blockIdx.y * 128;
  const unsigned short* bsrc0 = Bt + (size_t)(n0 + (tid >> 2)) * ldb + (tid & 3) * 8;
  const unsigned short* bsrc1 = bsrc0 + (size_t)64 * ldb;
  const int rr = lane & 15;
  const int kc = (((lane >> 4) ^ Frow(rr)) & 3) * 8;

  f4v acc[4][4] = {};
  for (int k0 = 0; k0 < Kp; k0 += 32) {
#pragma unroll
    for (int it = 0; it < 4; ++it) {
      const int r = it * 32 + (tid >> 3), c = (tid & 7) * 4;
      const float4 v = *(const float4*)(A + (size_t)(m0 + r) * lda + k0 + c);
      ushort4 w;
      w.x = f2b(v.x); w.y = f2b(v.y); w.z = f2b(v.z); w.w = f2b(v.w);
      *(ushort4*)&As[r * 32 + (c ^ (Frow(r & 15) << 3))] = w;
    }
    gload16(bsrc0 + k0, &Bs[tid * 8]);
    gload16(bsrc1 + k0, &Bs[2048 + tid * 8]);
    __syncthreads();
    s8v a[4], b[4];
#pragma unroll
    for (int i = 0; i < 4; ++i) a[i] = *(const s8v*)&As[(wm + i * 16 + rr) * 32 + kc];
#pragma unroll
    for (int j = 0; j < 4; ++j) b[j] = *(const s8v*)&Bs[(wn + j * 16 + rr) * 32 + kc];
#pragma unroll
    for (int i = 0; i < 4; ++i)
#pragma unroll
      for (int j = 0; j < 4; ++j)
        acc[i][j] = __builtin_amdgcn_mfma_f32_16x16x32_bf16(a[i], b[j], acc[i][j], 0, 0, 0);
    __syncthreads();
  }
  const int cr = (lane >> 4) * 4, cc = lane & 15;
#pragma unroll
  for (int i = 0; i < 4; ++i)
#pragma unroll
    for (int j = 0; j < 4; ++j) {
      const int gn = n0 + wn + j * 16 + cc;
      if (gn >= N) continue;
#pragma unroll
      for (int r = 0; r < 4; ++r)
        C[(size_t)(m0 + wm + i * 16 + cr + r) * ldc + gn] = f2b(acc[i][j][r] + bias[gn]);
    }
}

// =================== fp32 GEMM (setup-only) ===================
__global__ __launch_bounds__(256)
void gemm_f32(const float* __restrict__ Ap, int lda,
              const float* __restrict__ Bp, int ldb,
              float* __restrict__ Cp, int ldc,
              const float* __restrict__ bias,
              int M, int N, int K)
{
  __shared__ float As[16][64];
  __shared__ float Bs[16][64];
  const int n0 = blockIdx.x * 64, m0 = blockIdx.y * 64;
  const int tid = threadIdx.x;
  const int tx = tid & 15, ty = tid >> 4;
  float acc[4][4] = {};
  for (int k0 = 0; k0 < K; k0 += 16) {
    {
      const int e = tid << 2;
      const int m = e >> 4, k = e & 15;
      const int gm = m0 + m, gk = k0 + k;
      float4 v = make_float4(0.f, 0.f, 0.f, 0.f);
      if (gm < M) {
        const float* src = Ap + (size_t)gm * lda + gk;
        if (gk + 3 < K) v = *(const float4*)src;
        else {
          if (gk     < K) v.x = src[0];
          if (gk + 1 < K) v.y = src[1];
          if (gk + 2 < K) v.z = src[2];
          if (gk + 3 < K) v.w = src[3];
        }
      }
      As[k][m] = v.x; As[k + 1][m] = v.y; As[k + 2][m] = v.z; As[k + 3][m] = v.w;
    }
    {
      const int e = tid << 2;
      const int k = e >> 6, n = e & 63;
      const int gk = k0 + k, gn = n0 + n;
      float4 v = make_float4(0.f, 0.f, 0.f, 0.f);
      if (gk < K) {
        const float* src = Bp + (size_t)gk * ldb + gn;
        if (gn + 3 < N) v = *(const float4*)src;
        else {
          if (gn     < N) v.x = src[0];
          if (gn + 1 < N) v.y = src[1];
          if (gn + 2 < N) v.z = src[2];
          if (gn + 3 < N) v.w = src[3];
        }
      }
      Bs[k][n] = v.x; Bs[k][n + 1] = v.y; Bs[k][n + 2] = v.z; Bs[k][n + 3] = v.w;
    }
    __syncthreads();
#pragma unroll
    for (int k = 0; k < 16; ++k) {
      const float a0 = As[k][ty * 4 + 0], a1 = As[k][ty * 4 + 1];
      const float a2 = As[k][ty * 4 + 2], a3 = As[k][ty * 4 + 3];
      const float b0 = Bs[k][tx * 4 + 0], b1 = Bs[k][tx * 4 + 1];
      const float b2 = Bs[k][tx * 4 + 2], b3 = Bs[k][tx * 4 + 3];
      acc[0][0] += a0 * b0; acc[0][1] += a0 * b1; acc[0][2] += a0 * b2; acc[0][3] += a0 * b3;
      acc[1][0] += a1 * b0; acc[1][1] += a1 * b1; acc[1][2] += a1 * b2; acc[1][3] += a1 * b3;
      acc[2][0] += a2 * b0; acc[2][1] += a2 * b1; acc[2][2] += a2 * b2; acc[2][3] += a2 * b3;
      acc[3][0] += a3 * b0; acc[3][1] += a3 * b1; acc[3][2] += a3 * b2; acc[3][3] += a3 * b3;
    }
    __syncthreads();
  }
#pragma unroll
  for (int i = 0; i < 4; ++i) {
    const int gm = m0 + ty * 4 + i;
    if (gm >= M) continue;
#pragma unroll
    for (int j = 0; j < 4; ++j) {
      const int gn = n0 + tx * 4 + j;
      if (gn >= N) continue;
      Cp[(size_t)gm * ldc + gn] = acc[i][j] + bias[gn];
    }
  }
}

// =================== weight transpose+convert (swizzled dst) ===================
__global__ void convB_k(const float* __restrict__ src, int srcld, int K, int N,
                        unsigned short* __restrict__ dst, int dstld, int coff, int mode)
{
  __shared__ float t[32][33];
  const int kb = blockIdx.x * 32, nb = blockIdx.y * 32;
  const int tx = threadIdx.x & 31, ty = threadIdx.x >> 5;
#pragma unroll
  for (int i = 0; i < 32; i += 8) {
    const int k = kb + ty + i, n = nb + tx;
    t[ty + i][tx] = (k < K && n < N) ? src[(size_t)k * srcld + n] : 0.f;
  }
  __syncthreads();
#pragma unroll
  for (int i = 0; i < 32; i += 8) {
    const int n = nb + ty + i, k = kb + tx;
    if (n >= N || k >= K) continue;
    const float x = t[tx][ty + i];
    const int Fs = Frow(n & 15) << 3;
    unsigned short* row = dst + (size_t)n * dstld;
    if (mode == 0) {
      const unsigned short h = f2b(x);
      const unsigned short l = f2b(x - b2f(h));
      const int kq = coff + 3 * k;
      row[kq ^ Fs] = h;
      row[(kq + 1) ^ Fs] = h;
      row[(kq + 2) ^ Fs] = l;
    } else {
      row[(coff + k) ^ Fs] = f2b(x);
    }
  }
}

__global__ void zpad_k(unsigned short* __restrict__ dst, int ld, int c0, int N)
{
  const int w = ld - c0;
  const int idx = blockIdx.x * 256 + threadIdx.x;
  if (idx >= N * w) return;
  const int n = idx / w, c = c0 + (idx % w);
  dst[(size_t)n * ld + (c ^ (Frow(n & 15) << 3))] = 0;
}

__global__ void zfill_k(unsigned short* __restrict__ p, int n)
{
  const int i = blockIdx.x * 256 + threadIdx.x;
  if (i < n) p[i] = 0;
}

// =================== small kernels ===================
__global__ void feat_mean_k(const float* __restrict__ feat, float* __restrict__ fm)
{
  const int idx = blockIdx.x * 256 + threadIdx.x;
  if (idx >= NB * VD) return;
  const int d = idx % VD, b = idx / VD;
  const float* base = feat + (size_t)b * NR * VD + d;
  float s = 0.f;
  for (int r = 0; r < NR; ++r) s += base[(size_t)r * VD];
  fm[idx] = s * (1.f / NR);
}

__global__ void f2b8_k(const float* __restrict__ in, unsigned short* __restrict__ out, long n8)
{
  for (long i = blockIdx.x * 256 + threadIdx.x; i < n8; i += (long)gridDim.x * 256) {
    const float4 a = *(const float4*)(in + i * 8);
    const float4 b = *(const float4*)(in + i * 8 + 4);
    unsigned short w[8] = {f2b(a.x), f2b(a.y), f2b(a.z), f2b(a.w),
                           f2b(b.x), f2b(b.y), f2b(b.z), f2b(b.w)};
    const long row = i >> 8;
    const int  c   = (int)(i & 255) * 8;
    *(s8v*)(out + row * VD + (c ^ (Frow((int)row & 15) << 3))) = *(const s8v*)w;
  }
}

__global__ void build_x2_k(const int* __restrict__ cap, const float* __restrict__ emb,
                           const float* __restrict__ vinp, unsigned short* __restrict__ X2)
{
  const int idx = blockIdx.x * 256 + threadIdx.x;
  if (idx >= NB * NT * X2LD) return;
  const int c = idx % X2LD;
  const int bt = idx / X2LD;
  const int t = bt % NT, b = bt / NT;
  const int Fs = Frow(b & 15) << 3;
  unsigned short val = 0;
  if (c < 900) {
    const int d = c / 3, s = c % 3;
    const float v = (t == 0) ? vinp[b * IND + d]
                             : emb[(size_t)cap[b * (NT - 1) + (t - 1)] * IND + d];
    const unsigned short h = f2b(v);
    val = (s == 1) ? f2b(v - b2f(h)) : h;
  }
  X2[(size_t)bt * X2LD + (c ^ Fs)] = val;
}

__global__ void lstm_pw_v_k(const float* __restrict__ gp, const float* __restrict__ fmg,
                            float* __restrict__ cv,
                            unsigned short* __restrict__ A2c, unsigned short* __restrict__ A2v)
{
  const int idx = blockIdx.x * 256 + threadIdx.x;
  if (idx >= NB * NH) return;
  const int n = idx & (NH - 1), b = idx >> 10;
  const size_t base = (size_t)b * H4;
  float gi = fmg[base + n], gf = fmg[base + NH + n];
  float gg = fmg[base + 2 * NH + n], go = fmg[base + 3 * NH + n];
#pragma unroll
  for (int z = 0; z < ZGV; ++z) {
    const float* g = gp + (size_t)z * NB * H4 + base;
    gi += g[n]; gf += g[NH + n]; gg += g[2 * NH + n]; go += g[3 * NH + n];
  }
  const float c2 = sigm(gf) * cv[idx] + sigm(gi) * tanhf(gg);
  const float h2 = sigm(go) * tanhf(c2);
  cv[idx] = c2;
  const int Fs = Frow(b & 15) << 3;
  store3(A2c + (size_t)b * KGC, 6144 + 3 * n, h2, Fs);
  store3(A2v + (size_t)b * A2VLD, 3072 + 3 * n, h2, Fs);
}

__global__ void lstm_pw_c_k(const float* __restrict__ gp, const float* __restrict__ bc,
                            float* __restrict__ cc,
                            unsigned short* __restrict__ A2v, unsigned short* __restrict__ A2c,
                            unsigned short* __restrict__ outh2, int t)
{
  const int idx = blockIdx.x * 256 + threadIdx.x;
  if (idx >= NB * NH) return;
  const int n = idx & (NH - 1), b = idx >> 10;
  const size_t base = (size_t)b * H4;
  float gi = bc[n], gf = bc[NH + n], gg = bc[2 * NH + n], go = bc[3 * NH + n];
#pragma unroll
  for (int z = 0; z < ZGC; ++z) {
    const float* g = gp + (size_t)z * NB * H4 + base;
    gi += g[n]; gf += g[NH + n]; gg += g[2 * NH + n]; go += g[3 * NH + n];
  }
  const float c2 = sigm(gf) * cc[idx] + sigm(gi) * tanhf(gg);
  const float h2 = sigm(go) * tanhf(c2);
  cc[idx] = c2;
  const int Fs = Frow(b & 15) << 3;
  store3(A2v + (size_t)b * A2VLD, 3 * n, h2, Fs);
  store3(A2c + (size_t)b * KGC, 9216 + 3 * n, h2, Fs);
  const int ro = b * NT + t;
  store3(outh2 + (size_t)ro * KCL, 3 * n, h2, Frow(ro & 15) << 3);
}

// attention logits with ha reduction fused: grid (4 rgroups, NB)
__global__ __launch_bounds__(256)
void att_logits_k(const unsigned short* __restrict__ va16,
                  const float* __restrict__ hap,   // [ZHA][NB][NH]
                  const float* __restrict__ bha,
                  const float* __restrict__ Wa, const float* __restrict__ ba,
                  float* __restrict__ logits)
{
  const int rg = blockIdx.x, b = blockIdx.y;
  const int tid = threadIdx.x, lane = tid & 63, wid = tid >> 6;
  __shared__ float ha_s[NH];
  __shared__ float wa_s[NH];
  for (int j = tid; j < NH; j += 256) {
    float s = bha[j];
#pragma unroll
    for (int z = 0; z < ZHA; ++z) s += hap[((size_t)z * NB + b) * NH + j];
    ha_s[j] = s;
    wa_s[j] = Wa[j];
  }
  __syncthreads();
  for (int r0 = wid; r0 < 25; r0 += 4) {
    const int r = rg * 25 + r0;
    const unsigned short* vrow = va16 + ((size_t)b * NR + r) * NH + lane * 16;
    float s = 0.f;
#pragma unroll
    for (int u = 0; u < 2; ++u) {
      const s8v v = *(const s8v*)(vrow + u * 8);
      const int j0 = lane * 16 + u * 8;
#pragma unroll
      for (int e = 0; e < 8; ++e)
        s += tanhf(b2f((unsigned short)v[e]) + ha_s[j0 + e]) * wa_s[j0 + e];
    }
    for (int o = 32; o; o >>= 1) s += __shfl_down(s, o);
    if (lane == 0) logits[b * NR + r] = s + ba[0];
  }
}

// softmax + feat_hat + pack: grid NB, 256 thr
template<bool F16>
__global__ __launch_bounds__(256)
void att_fh_k(const float* __restrict__ logits,
              const unsigned short* __restrict__ f16,
              const float* __restrict__ f32,
              unsigned short* __restrict__ A2c,
              float* __restrict__ att_out, int t)
{
  const int b = blockIdx.x, tid = threadIdx.x;
  const int lane = tid & 63, wid = tid >> 6;
  __shared__ float red_s[128];
  if (tid < 128) red_s[tid] = (tid < NR) ? logits[b * NR + tid] : -3.4e38f;
  __syncthreads();
  if (wid == 0) {
    float v0 = red_s[lane];
    float v1 = red_s[lane + 64];
    float m = fmaxf(v0, v1);
    for (int o = 32; o; o >>= 1) m = fmaxf(m, __shfl_xor(m, o));
    const float e0 = (lane < NR) ? expf(v0 - m) : 0.f;
    const float e1 = (lane + 64 < NR) ? expf(v1 - m) : 0.f;
    float s = e0 + e1;
    for (int o = 32; o; o >>= 1) s += __shfl_xor(s, o);
    const float inv = 1.f / s;
    red_s[lane] = e0 * inv;
    red_s[lane + 64] = e1 * inv;
  }
  __syncthreads();
  if (tid < NR) att_out[((size_t)b * NT + t) * NR + tid] = red_s[tid];

  const int d0 = tid * 8;
  float fh[8] = {};
  if constexpr (F16) {
    const unsigned short* fbase = f16 + (size_t)b * NR * VD;
    for (int r = 0; r < NR; ++r) {
      const int ro = b * NR + r;
      const s8v f = *(const s8v*)(fbase + (size_t)r * VD + (d0 ^ (Frow(ro & 15) << 3)));
      const float a = red_s[r];
#pragma unroll
      for (int e = 0; e < 8; ++e) fh[e] += a * b2f((unsigned short)f[e]);
    }
  } else {
    const float* fb = f32 + (size_t)b * NR * VD + d0;
    for (int r = 0; r < NR; ++r) {
      const float4 x0 = *(const float4*)(fb + (size_t)r * VD);
      const float4 x1 = *(const float4*)(fb + (size_t)r * VD + 4);
      const float a = red_s[r];
      fh[0] += a * x0.x; fh[1] += a * x0.y; fh[2] += a * x0.z; fh[3] += a * x0.w;
      fh[4] += a * x1.x; fh[5] += a * x1.y; fh[6] += a * x1.z; fh[7] += a * x1.w;
    }
  }
  unsigned short* rowbase = A2c + (size_t)b * KGC;
  const int Fs = Frow(b & 15) << 3;
#pragma unroll
  for (int e = 0; e < 8; ++e) store3(rowbase, 3 * (d0 + e), fh[e] * (1.f / NR), Fs);
}

inline void gemmF(hipStream_t st, const float* A, int lda, const float* B, int ldb,
                  float* C, int ldc, const float* bias, int M, int N, int K)
{
  dim3 g((N + 63) / 64, (M + 63) / 64);
  gemm_f32<<<g, 256, 0, st>>>(A, lda, B, ldb, C, ldc, bias, M, N, K);
}

inline void convB(hipStream_t st, const float* src, int srcld, int K, int N,
                  unsigned short* dst, int dstld, int coff, int mode)
{
  dim3 g((K + 31) / 32, (N + 31) / 32);
  convB_k<<<g, 256, 0, st>>>(src, srcld, K, N, dst, dstld, coff, mode);
}

} // namespace

extern "C" void kernel_launch(void* const* d_in, const int* in_sizes, int n_in,
                              void* d_out, int out_size, void* d_ws, size_t ws_size,
                              hipStream_t stream)
{
  const int*   caption = (const int*)  d_in[0];
  const float* feat    = (const float*)d_in[1];
  const float* emb     = (const float*)d_in[2];
  const float* W_vin   = (const float*)d_in[3];
  const float* b_vin   = (const float*)d_in[4];
  const float* W_ih_v  = (const float*)d_in[5];
  const float* W_hh_v  = (const float*)d_in[6];
  const float* b_v     = (const float*)d_in[7];
  const float* W_va    = (const float*)d_in[8];
  const float* b_va    = (const float*)d_in[9];
  const float* W_ha    = (const float*)d_in[10];
  const float* b_ha    = (const float*)d_in[11];
  const float* W_a     = (const float*)d_in[12];
  const float* b_a     = (const float*)d_in[13];
  const float* W_ih_c  = (const float*)d_in[14];
  const float* W_hh_c  = (const float*)d_in[15];
  const float* b_c     = (const float*)d_in[16];
  const float* W_cls   = (const float*)d_in[17];
  const float* b_cls   = (const float*)d_in[18];

  float* out_repr = (float*)d_out;                       // [NB,NT,VOC]
  float* out_att  = out_repr + (size_t)NB * NT * VOC;    // [NB,NT,NR]

  char* cur = (char*)d_ws;
  auto take = [&](size_t bytes) { char* p = cur; cur += bytes; return p; };

  unsigned short* A2v  = (unsigned short*)take((size_t)NB * A2VLD * 2);
  unsigned short* A2c  = (unsigned short*)take((size_t)NB * KGC * 2);
  float* CV            = (float*)take((size_t)NB * NH * 4);
  float* CC            = (float*)take((size_t)NB * NH * 4);
  const size_t ZERO_BYTES = (size_t)NB * A2VLD * 2 + (size_t)NB * KGC * 2
                          + 2 * (size_t)NB * NH * 4;

  float* FM            = (float*)take((size_t)NB * VD * 4);
  float* VINP          = (float*)take((size_t)NB * IND * 4);
  unsigned short* X2   = (unsigned short*)take((size_t)NB * NT * X2LD * 2);
  float* FMG           = (float*)take((size_t)NB * H4 * 4);
  unsigned short* VA16 = (unsigned short*)take((size_t)NB * NR * NH * 2);   // 52MB
  float* GP            = (float*)take((size_t)ZGC * NB * H4 * 4);           // 33.5MB
  float* HAP           = (float*)take((size_t)ZHA * NB * NH * 4);           // 8.4MB
  float* LOG           = (float*)take((size_t)NB * NR * 4);
  unsigned short* OUTH2= (unsigned short*)take((size_t)NB * NT * KCL * 2);  // 31.5MB
  unsigned short* Wgv2t= (unsigned short*)take((size_t)H4 * KGV * 2);       // 58MB
  unsigned short* Wha2t= (unsigned short*)take((size_t)NH * KHA * 2);
  unsigned short* Wgc2t= (unsigned short*)take((size_t)H4 * KGC * 2);       // 101MB
  unsigned short* Wcls2t=(unsigned short*)take((size_t)VOCP2 * KCL * 2);    // 63MB
  unsigned short* Wva16t=(unsigned short*)take((size_t)NH * VD * 2);
  unsigned short* FEAT16=(unsigned short*)cur;                              // 105MB optional
  const bool useF16 = ((size_t)(cur - (char*)d_ws) + (size_t)NB * NR * VD * 2) <= ws_size;

  hipMemsetAsync(A2v, 0, ZERO_BYTES, stream);

  // ---- weight conversions (swizzled) ----
  convB(stream, W_ih_v + (size_t)2048 * H4, H4, 1024, H4, Wgv2t, KGV, 0,    0);
  convB(stream, W_hh_v,                     H4, 1024, H4, Wgv2t, KGV, 3072, 0);
  convB(stream, W_ih_v + (size_t)3072 * H4, H4, 300,  H4, Wgv2t, KGV, 6144, 0);
  zpad_k<<<((H4 * (KGV - 7044)) + 255) / 256, 256, 0, stream>>>(Wgv2t, KGV, 7044, H4);
  convB(stream, W_ha, NH, 1024, NH, Wha2t, KHA, 0, 0);
  convB(stream, W_ih_c,                     H4, 2048, H4, Wgc2t, KGC, 0,    0);
  convB(stream, W_ih_c + (size_t)2048 * H4, H4, 1024, H4, Wgc2t, KGC, 6144, 0);
  convB(stream, W_hh_c,                     H4, 1024, H4, Wgc2t, KGC, 9216, 0);
  convB(stream, W_cls, VOC, 1024, VOC, Wcls2t, KCL, 0, 0);
  zfill_k<<<(((VOCP2 - VOC) * KCL) + 255) / 256, 256, 0, stream>>>(
      Wcls2t + (size_t)VOC * KCL, (VOCP2 - VOC) * KCL);
  convB(stream, W_va, NH, VD, NH, Wva16t, VD, 0, 1);

  // ---- setup ----
  feat_mean_k<<<(NB * VD + 255) / 256, 256, 0, stream>>>(feat, FM);
  gemmF(stream, FM, VD, W_vin, IND, VINP, IND, b_vin, NB, IND, VD);
  build_x2_k<<<(NB * NT * X2LD + 255) / 256, 256, 0, stream>>>(caption, emb, VINP, X2);
  gemmF(stream, FM, VD, W_ih_v, H4, FMG, H4, b_v, NB, H4, VD);
  if (useF16) {
    f2b8_k<<<2048, 256, 0, stream>>>(feat, FEAT16, (long)NB * NR * VD / 8);
    dim3 g((NB * NR) / 256, NH / 256);
    gemm256<true><<<g, 512, 0, stream>>>(FEAT16, VD, Wva16t, VD, VA16, NH, b_va, NH, VD);
  } else {
    dim3 g((NB * NR) / 128, NH / 128);
    gemm_va_f32<<<g, 256, 0, stream>>>(feat, VD, Wva16t, VD, VA16, NH, b_va, NH, VD);
  }

  // ---- sequential decode ----
  for (int t = 0; t < NT; ++t) {
    gemm_sk2<true><<<dim3(H4 / 128, 1, ZGV), 512, 0, stream>>>(
        A2v, A2VLD, X2, t, Wgv2t, KGV, GP, H4, KGV, KSV);
    lstm_pw_v_k<<<(NB * NH + 255) / 256, 256, 0, stream>>>(GP, FMG, CV, A2c, A2v);
    gemm_sk2<false><<<dim3(NH / 128, 1, ZHA), 512, 0, stream>>>(
        A2c + 6144, KGC, nullptr, 0, Wha2t, KHA, HAP, NH, KHA, KSH);
    att_logits_k<<<dim3(4, NB), 256, 0, stream>>>(VA16, HAP, b_ha, W_a, b_a, LOG);
    if (useF16)
      att_fh_k<true><<<NB, 256, 0, stream>>>(LOG, FEAT16, nullptr, A2c, out_att, t);
    else
      att_fh_k<false><<<NB, 256, 0, stream>>>(LOG, nullptr, feat, A2c, out_att, t);
    gemm_sk2<false><<<dim3(H4 / 128, 1, ZGC), 512, 0, stream>>>(
        A2c, KGC, nullptr, 0, Wgc2t, KGC, GP, H4, KGC, KSC);
    lstm_pw_c_k<<<(NB * NH + 255) / 256, 256, 0, stream>>>(GP, b_c, CC, A2v, A2c, OUTH2, t);
  }

  // ---- classifier: 256x256 tiles, depth-3 pipeline ----
  {
    dim3 g((NB * NT) / 256, VOCP2 / 256);
    gemm256<false><<<g, 512, 0, stream>>>(
        OUTH2, KCL, Wcls2t, KCL, out_repr, VOC, b_cls, VOC, KCL);
  }
}